// Round 6
// baseline (354.211 us; speedup 1.0000x reference)
//
#include <hip/hip_runtime.h>
#include <hip/hip_bf16.h>
#include <hip/hip_fp16.h>
#include <hip/hip_cooperative_groups.h>
#include <math.h>

namespace cg = cooperative_groups;

#define N_NODES 50000
#define N_EDGES 800000
#define HC      128     // HEADS*HID
#define OUTD    64

// fast exp2: single v_exp_f32
#if defined(__has_builtin)
#if __has_builtin(__builtin_amdgcn_exp2f)
#define EXP2(x) __builtin_amdgcn_exp2f(x)
#endif
#endif
#ifndef EXP2
#define EXP2(x) __expf((x) * 0.69314718055994531f)
#endif

// ---------------- fused CSR build + weight prep (one cooperative kernel) ----
// Replaces 7 dispatches (memset, deg, scan_up, scan_mid, scan_down, fill,
// prep) with 1; grid 49x1024 is trivially co-resident (needs 25 CUs of 256).

__global__ void k_csr(const int* __restrict__ src, const int* __restrict__ dst,
                      int* __restrict__ deg, int* __restrict__ off,
                      int* __restrict__ cur, int* __restrict__ esrc,
                      int* __restrict__ bsum, int* __restrict__ boff,
                      const float* __restrict__ W0, const float* __restrict__ W1,
                      const float* __restrict__ pW1, const float* __restrict__ pb1,
                      const float* __restrict__ pW2, const float* __restrict__ pb2,
                      float* __restrict__ Wt0, float* __restrict__ Wt1,
                      float* __restrict__ Wct, float* __restrict__ bc) {
    cg::grid_group grid = cg::this_grid();
    const int gsz  = gridDim.x * blockDim.x;          // 49*1024 = 50176
    const int gtid = blockIdx.x * blockDim.x + threadIdx.x;
    const int PREP_TOT = HC * HC + HC * OUTD + OUTD;  // 24640

    // phase 0: zero deg + weight prep (prep result not needed until lin128)
    for (int i = gtid; i < N_NODES; i += gsz) deg[i] = 0;
    for (int i = gtid; i < PREP_TOT; i += gsz) {
        if (i < HC * HC) {
            int r = i >> 7, c = i & 127;
            Wt0[c * HC + r] = W0[i];
            Wt1[c * HC + r] = W1[i];
        } else if (i < HC * HC + HC * OUTD) {
            int j = i - HC * HC;
            int k = j >> 6, o2 = j & 63;
            float s = 0.f;
            for (int m = 0; m < 64; ++m) s += pW2[o2 * 64 + m] * pW1[m * 128 + k];
            Wct[k * 64 + o2] = s;
        } else {
            int o2 = i - HC * HC - HC * OUTD;
            float s = pb2[o2];
            for (int m = 0; m < 64; ++m) s += pW2[o2 * 64 + m] * pb1[m];
            bc[o2] = s;
        }
    }
    grid.sync();

    // phase 1: degree count
    for (int e = gtid; e < N_EDGES; e += gsz) atomicAdd(&deg[dst[e]], 1);
    grid.sync();

    // phase 2: block-local exclusive scan (gtid directly covers all nodes)
    {
        __shared__ int wsum[16];
        __shared__ int wexc[16];
        const int lane = threadIdx.x & 63;
        const int wid  = threadIdx.x >> 6;
        int i = gtid;
        int v = (i < N_NODES) ? deg[i] : 0;
        int incl = v;
        #pragma unroll
        for (int s = 1; s < 64; s <<= 1) {
            int t = __shfl_up(incl, s, 64);
            if (lane >= s) incl += t;
        }
        if (lane == 63) wsum[wid] = incl;
        __syncthreads();
        if (wid == 0 && lane < 16) {
            int w = wsum[lane];
            int wi = w;
            #pragma unroll
            for (int s = 1; s < 16; s <<= 1) {
                int t = __shfl_up(wi, s, 64);
                if (lane >= s) wi += t;
            }
            wexc[lane] = wi - w;
        }
        __syncthreads();
        int ex = wexc[wid] + incl - v;
        if (i < N_NODES) off[i] = ex;
        if (threadIdx.x == 1023) bsum[blockIdx.x] = ex + v;
    }
    grid.sync();

    // phase 3: block 0 scans the 49 block totals
    if (blockIdx.x == 0 && threadIdx.x < 64) {
        int lane = threadIdx.x;
        int nb = gridDim.x;
        int v = (lane < nb) ? bsum[lane] : 0;
        int incl = v;
        #pragma unroll
        for (int s = 1; s < 64; s <<= 1) {
            int t = __shfl_up(incl, s, 64);
            if (lane >= s) incl += t;
        }
        if (lane < nb) boff[lane] = incl - v;
        if (lane == 63) off[N_NODES] = incl;
    }
    grid.sync();

    // phase 4: add-down
    if (gtid < N_NODES) {
        int o = off[gtid] + boff[blockIdx.x];
        off[gtid] = o;
        cur[gtid] = o;
    }
    grid.sync();

    // phase 5: fill
    for (int e = gtid; e < N_EDGES; e += gsz) {
        int p = atomicAdd(&cur[dst[e]], 1);
        esrc[p] = src[e];
    }
}

// ---------------- linear: h = x @ Wt + b, K=128, OC=128, out fp16 ----------------
// LDS-staged weights. 32 nodes/block, Wt staged in two 32KB K-chunks,
// x staged once (16KB). 48KB LDS -> 3 blocks/CU.
// NOTE: macro params must not be named x/y/z/w (preprocessor substitutes
// member-access tokens -- round 3's compile failure).

#define FMA4(acc, wv, sv)                                                      \
    acc.x = fmaf(wv.x, sv, acc.x); acc.y = fmaf(wv.y, sv, acc.y);              \
    acc.z = fmaf(wv.z, sv, acc.z); acc.w = fmaf(wv.w, sv, acc.w);

__global__ __launch_bounds__(256) void k_lin128(const float* __restrict__ x,
                                                const float* __restrict__ Wt,
                                                const float* __restrict__ bias,
                                                __half* __restrict__ h, int n) {
    __shared__ float ws[64 * 128];      // 32KB: one K-chunk of Wt (rows = k)
    __shared__ float xs[32 * 128];      // 16KB: 32 node rows
    int t = threadIdx.x;
    int node0 = blockIdx.x * 32;
    for (int i = t; i < 1024; i += 256) {
        int row = i >> 5, c = i & 31;
        int gn = node0 + row;
        ((float4*)xs)[i] = (gn < n) ? ((const float4*)x)[(size_t)gn * 32 + c]
                                    : make_float4(0.f, 0.f, 0.f, 0.f);
    }
    int c4 = t & 31;                    // output float4 index [0,32)
    int ng = (t >> 5) * 4;              // first of my 4 nodes
    float4 bb = ((const float4*)bias)[c4];
    float4 a0 = bb, a1 = bb, a2 = bb, a3 = bb;
    const float4* xr0 = (const float4*)&xs[(ng + 0) * 128];
    const float4* xr1 = (const float4*)&xs[(ng + 1) * 128];
    const float4* xr2 = (const float4*)&xs[(ng + 2) * 128];
    const float4* xr3 = (const float4*)&xs[(ng + 3) * 128];

    for (int chunk = 0; chunk < 2; ++chunk) {
        __syncthreads();                // x ready (it=0) / ws no longer read (it=1)
        const float4* wsrc = (const float4*)&Wt[chunk * 64 * 128];
        for (int i = t; i < 2048; i += 256)
            ((float4*)ws)[i] = wsrc[i];
        __syncthreads();
        int kb = chunk * 16;
        #pragma unroll 4
        for (int k4 = 0; k4 < 16; ++k4) {
            float4 xv0 = xr0[kb + k4];
            float4 xv1 = xr1[kb + k4];
            float4 xv2 = xr2[kb + k4];
            float4 xv3 = xr3[kb + k4];
            const float* wr = &ws[k4 * 512];
            float4 w0 = ((const float4*)&wr[0])[c4];
            float4 w1 = ((const float4*)&wr[128])[c4];
            float4 w2 = ((const float4*)&wr[256])[c4];
            float4 w3 = ((const float4*)&wr[384])[c4];
            FMA4(a0, w0, xv0.x); FMA4(a0, w1, xv0.y); FMA4(a0, w2, xv0.z); FMA4(a0, w3, xv0.w);
            FMA4(a1, w0, xv1.x); FMA4(a1, w1, xv1.y); FMA4(a1, w2, xv1.z); FMA4(a1, w3, xv1.w);
            FMA4(a2, w0, xv2.x); FMA4(a2, w1, xv2.y); FMA4(a2, w2, xv2.z); FMA4(a2, w3, xv2.w);
            FMA4(a3, w0, xv3.x); FMA4(a3, w1, xv3.y); FMA4(a3, w2, xv3.z); FMA4(a3, w3, xv3.w);
        }
    }

    union { __half2 h2[2]; uint2 u; } p;
    int gn = node0 + ng;
    if (gn + 0 < n) { p.h2[0] = __floats2half2_rn(a0.x, a0.y); p.h2[1] = __floats2half2_rn(a0.z, a0.w);
                      *(uint2*)&h[(size_t)(gn + 0) * 128 + c4 * 4] = p.u; }
    if (gn + 1 < n) { p.h2[0] = __floats2half2_rn(a1.x, a1.y); p.h2[1] = __floats2half2_rn(a1.z, a1.w);
                      *(uint2*)&h[(size_t)(gn + 1) * 128 + c4 * 4] = p.u; }
    if (gn + 2 < n) { p.h2[0] = __floats2half2_rn(a2.x, a2.y); p.h2[1] = __floats2half2_rn(a2.z, a2.w);
                      *(uint2*)&h[(size_t)(gn + 2) * 128 + c4 * 4] = p.u; }
    if (gn + 3 < n) { p.h2[0] = __floats2half2_rn(a3.x, a3.y); p.h2[1] = __floats2half2_rn(a3.z, a3.w);
                      *(uint2*)&h[(size_t)(gn + 3) * 128 + c4 * 4] = p.u; }
}

// ---------------- GAT aggregate ----------------
// One wave per dst node, two half-waves by edge parity. Max-free log2-domain
// softmax (scores O(+-5), no overflow/flush possible; safety fallback below).
// Addressing diet vs round 5: uniform SGPR h base + 32-bit voffset
// (v_lshl_or_b32 + saddr global_load), strength-reduced shfl lane index
// (sl += 2), leaky via u = 0.2f*t (drops 8 constant VGPRs).

__global__ __launch_bounds__(256) void k_gat_agg(const __half* __restrict__ h,
                                                 const int* __restrict__ off,
                                                 const int* __restrict__ esrc,
                                                 const float* __restrict__ attl,
                                                 const float* __restrict__ attr,
                                                 float* __restrict__ xout, int n,
                                                 float neg_out) {
    const float L2E = 1.4426950408889634f;
    int wid  = threadIdx.x >> 6;
    int lane = threadIdx.x & 63;
    int node = blockIdx.x * 4 + wid;
    if (node >= n) return;
    int half = lane >> 5;               // edge parity this half-wave owns
    int cq   = lane & 31;               // channel quad index
    uint32_t cq8 = (uint32_t)cq << 3;   // byte offset of my 4 fp16 channels

    const char* hb = (const char*)h;    // uniform base (SGPR) -- saddr form

    float4 alv = ((const float4*)attl)[cq];
    float4 arv = ((const float4*)attr)[cq];
    uint2 hdr = *(const uint2*)(hb + ((((uint32_t)node << 8)) | cq8));
    float2 hd01 = __half22float2(((const __half2*)&hdr)[0]);
    float2 hd23 = __half22float2(((const __half2*)&hdr)[1]);
    float al0 = alv.x * L2E, al1 = alv.y * L2E;
    float al2 = alv.z * L2E, al3 = alv.w * L2E;
    float ar0 = arv.x * hd01.x * L2E, ar1 = arv.y * hd01.y * L2E;
    float ar2 = arv.z * hd23.x * L2E, ar3 = arv.w * hd23.y * L2E;

    float z0 = 0.f, z1 = 0.f, z2 = 0.f, z3 = 0.f;
    float a0 = 0.f, a1 = 0.f, a2 = 0.f, a3 = 0.f;

    int beg = off[node], end = off[node + 1];

#define STEP(sAv)                                                              \
    {   uint32_t voff = (((uint32_t)(sAv)) << 8) | cq8;                        \
        uint2 hv = *(const uint2*)(hb + voff);                                 \
        float2 f01 = __half22float2(((const __half2*)&hv)[0]);                 \
        float2 f23 = __half22float2(((const __half2*)&hv)[1]);                 \
        float t0 = fmaf(al0, f01.x, ar0), t1 = fmaf(al1, f01.y, ar1);          \
        float t2 = fmaf(al2, f23.x, ar2), t3 = fmaf(al3, f23.y, ar3);          \
        float e0 = EXP2(fmaxf(t0, 0.2f * t0)), e1 = EXP2(fmaxf(t1, 0.2f * t1));\
        float e2 = EXP2(fmaxf(t2, 0.2f * t2)), e3 = EXP2(fmaxf(t3, 0.2f * t3));\
        z0 += e0; z1 += e1; z2 += e2; z3 += e3;                                \
        a0 = fmaf(e0, f01.x, a0); a1 = fmaf(e1, f01.y, a1);                    \
        a2 = fmaf(e2, f23.x, a2); a3 = fmaf(e3, f23.y, a3);                    \
    }

    for (int cbeg = beg; cbeg < end; cbeg += 64) {
        int cnt = end - cbeg; if (cnt > 64) cnt = 64;
        int myS = (cbeg + lane < end) ? esrc[cbeg + lane] : 0;
        int fullp = cnt >> 1;           // steps where both halves have an edge
        int sl = half;                  // strength-reduced shfl index
        #pragma unroll 4
        for (int t = 0; t < fullp; ++t) {
            int sA = __shfl(myS, sl, 64);   // all 64 lanes active
            sl += 2;
            STEP(sA);
        }
        if (cnt & 1) {                  // one leftover even-parity edge
            int sA = __shfl(myS, cnt - 1, 64);
            if (half == 0) STEP(sA);
        }
    }
#undef STEP

    // validity: overflow -> z inf/NaN; total underflow -> z==0 with edges
    float zs = z0 + z1 + z2 + z3;
    bool bad = !(zs < 3.0e38f);
    if (beg < end)
        bad = bad || !((z0 > 0.f) && (z1 > 0.f) && (z2 > 0.f) && (z3 > 0.f));

    if (__any(bad)) {
        // slow safe path (~never): two-pass max-shifted softmax; every lane
        // walks ALL edges, so both halves hold identical full sums (no merge).
        float m0 = -1e30f, m1 = -1e30f, m2 = -1e30f, m3 = -1e30f;
        for (int cbeg = beg; cbeg < end; cbeg += 64) {
            int cnt = end - cbeg; if (cnt > 64) cnt = 64;
            int myS = (cbeg + lane < end) ? esrc[cbeg + lane] : 0;
            for (int t = 0; t < cnt; ++t) {
                int sA = __shfl(myS, t, 64);
                uint2 hv = *(const uint2*)(hb + (((uint32_t)sA << 8) | cq8));
                float2 f01 = __half22float2(((const __half2*)&hv)[0]);
                float2 f23 = __half22float2(((const __half2*)&hv)[1]);
                float t0 = fmaf(al0, f01.x, ar0), t1 = fmaf(al1, f01.y, ar1);
                float t2 = fmaf(al2, f23.x, ar2), t3 = fmaf(al3, f23.y, ar3);
                m0 = fmaxf(m0, fmaxf(t0, 0.2f * t0));
                m1 = fmaxf(m1, fmaxf(t1, 0.2f * t1));
                m2 = fmaxf(m2, fmaxf(t2, 0.2f * t2));
                m3 = fmaxf(m3, fmaxf(t3, 0.2f * t3));
            }
        }
        z0 = z1 = z2 = z3 = 0.f;
        a0 = a1 = a2 = a3 = 0.f;
        for (int cbeg = beg; cbeg < end; cbeg += 64) {
            int cnt = end - cbeg; if (cnt > 64) cnt = 64;
            int myS = (cbeg + lane < end) ? esrc[cbeg + lane] : 0;
            for (int t = 0; t < cnt; ++t) {
                int sA = __shfl(myS, t, 64);
                uint2 hv = *(const uint2*)(hb + (((uint32_t)sA << 8) | cq8));
                float2 f01 = __half22float2(((const __half2*)&hv)[0]);
                float2 f23 = __half22float2(((const __half2*)&hv)[1]);
                float t0 = fmaf(al0, f01.x, ar0), t1 = fmaf(al1, f01.y, ar1);
                float t2 = fmaf(al2, f23.x, ar2), t3 = fmaf(al3, f23.y, ar3);
                float e0 = EXP2(fmaxf(t0, 0.2f * t0) - m0);
                float e1 = EXP2(fmaxf(t1, 0.2f * t1) - m1);
                float e2 = EXP2(fmaxf(t2, 0.2f * t2) - m2);
                float e3 = EXP2(fmaxf(t3, 0.2f * t3) - m3);
                z0 += e0; z1 += e1; z2 += e2; z3 += e3;
                a0 = fmaf(e0, f01.x, a0); a1 = fmaf(e1, f01.y, a1);
                a2 = fmaf(e2, f23.x, a2); a3 = fmaf(e3, f23.y, a3);
            }
        }
    } else {
        // merge parity halves: plain adds (shared implicit reference)
        z0 += __shfl_xor(z0, 32, 64); z1 += __shfl_xor(z1, 32, 64);
        z2 += __shfl_xor(z2, 32, 64); z3 += __shfl_xor(z3, 32, 64);
        a0 += __shfl_xor(a0, 32, 64); a1 += __shfl_xor(a1, 32, 64);
        a2 += __shfl_xor(a2, 32, 64); a3 += __shfl_xor(a3, 32, 64);
    }

    if (half == 0) {
        float o0 = (z0 > 0.f) ? a0 / z0 : 0.f;
        float o1 = (z1 > 0.f) ? a1 / z1 : 0.f;
        float o2 = (z2 > 0.f) ? a2 / z2 : 0.f;
        float o3 = (z3 > 0.f) ? a3 / z3 : 0.f;
        o0 = fmaxf(o0, neg_out * o0);
        o1 = fmaxf(o1, neg_out * o1);
        o2 = fmaxf(o2, neg_out * o2);
        o3 = fmaxf(o3, neg_out * o3);
        *(float4*)&xout[(size_t)node * 128 + cq * 4] = make_float4(o0, o1, o2, o3);
    }
}

// ---------------- final linear K=128 -> 64: LDS-staged Wct ----------------

__global__ __launch_bounds__(256) void k_lin64(const float* __restrict__ x,
                                               const float* __restrict__ Wct,
                                               const float* __restrict__ bc,
                                               float* __restrict__ y,
                                               __half* __restrict__ yh, int n) {
    __shared__ float ws[128 * 64];      // 32KB, row k: 64 outputs
    __shared__ float xs[32 * 128];      // 16KB
    int t = threadIdx.x;
    int node0 = blockIdx.x * 32;
    for (int i = t; i < 2048; i += 256)
        ((float4*)ws)[i] = ((const float4*)Wct)[i];
    for (int i = t; i < 1024; i += 256) {
        int row = i >> 5, c = i & 31;
        int gn = node0 + row;
        ((float4*)xs)[i] = (gn < n) ? ((const float4*)x)[(size_t)gn * 32 + c]
                                    : make_float4(0.f, 0.f, 0.f, 0.f);
    }
    __syncthreads();
    int l = t & 15;                     // output float4 index [0,16)
    int ng = (t >> 4) * 2;              // first of my 2 nodes
    float4 bb = ((const float4*)bc)[l];
    float4 a0 = bb, a1 = bb;
    const float4* xr0 = (const float4*)&xs[(ng + 0) * 128];
    const float4* xr1 = (const float4*)&xs[(ng + 1) * 128];
    #pragma unroll 4
    for (int k4 = 0; k4 < 32; ++k4) {
        float4 xv0 = xr0[k4];
        float4 xv1 = xr1[k4];
        const float* wr = &ws[k4 * 256];
        float4 w0 = ((const float4*)&wr[0])[l];
        float4 w1 = ((const float4*)&wr[64])[l];
        float4 w2 = ((const float4*)&wr[128])[l];
        float4 w3 = ((const float4*)&wr[192])[l];
        FMA4(a0, w0, xv0.x); FMA4(a0, w1, xv0.y); FMA4(a0, w2, xv0.z); FMA4(a0, w3, xv0.w);
        FMA4(a1, w0, xv1.x); FMA4(a1, w1, xv1.y); FMA4(a1, w2, xv1.z); FMA4(a1, w3, xv1.w);
    }
    union { __half2 h2[2]; uint2 u; } p;
    int gn = node0 + ng;
    if (gn + 0 < n) {
        ((float4*)&y[(size_t)(gn + 0) * 64])[l] = a0;
        p.h2[0] = __floats2half2_rn(a0.x, a0.y); p.h2[1] = __floats2half2_rn(a0.z, a0.w);
        *(uint2*)&yh[(size_t)(gn + 0) * 64 + l * 4] = p.u;
    }
    if (gn + 1 < n) {
        ((float4*)&y[(size_t)(gn + 1) * 64])[l] = a1;
        p.h2[0] = __floats2half2_rn(a1.x, a1.y); p.h2[1] = __floats2half2_rn(a1.z, a1.w);
        *(uint2*)&yh[(size_t)(gn + 1) * 64 + l * 4] = p.u;
    }
}

// ---------------- edge scores: sigmoid(dot(x[src], x[dst])), fp16 gather, 8 lanes/edge ----------------

__global__ __launch_bounds__(256) void k_edge_score(const __half* __restrict__ xh,
                                                    const int* __restrict__ src,
                                                    const int* __restrict__ dst,
                                                    float* __restrict__ out, int e_cnt) {
    int t = blockIdx.x * 256 + threadIdx.x;
    int e = t >> 3;
    int l = t & 7;
    if (e >= e_cnt) return;
    int u = src[e], v = dst[e];
    uint4 ua = ((const uint4*)&xh[(size_t)u * 64])[l];
    uint4 vb = ((const uint4*)&xh[(size_t)v * 64])[l];
    const __half2* pa = (const __half2*)&ua;
    const __half2* pb = (const __half2*)&vb;
    float d = 0.f;
    #pragma unroll
    for (int j = 0; j < 4; ++j) {
        float2 fa = __half22float2(pa[j]);
        float2 fb = __half22float2(pb[j]);
        d = fmaf(fa.x, fb.x, d);
        d = fmaf(fa.y, fb.y, d);
    }
    d += __shfl_xor(d, 1);
    d += __shfl_xor(d, 2);
    d += __shfl_xor(d, 4);
    if (l == 0) out[e] = 1.f / (1.f + __expf(-d));
}

// ---------------- launch ----------------

extern "C" void kernel_launch(void* const* d_in, const int* in_sizes, int n_in,
                              void* d_out, int out_size, void* d_ws, size_t ws_size,
                              hipStream_t stream) {
    const float* emb   = (const float*)d_in[0];
    const int*   ei    = (const int*)d_in[1];
    const float* W0    = (const float*)d_in[2];
    const float* b0    = (const float*)d_in[3];
    const float* attl0 = (const float*)d_in[4];
    const float* attr0 = (const float*)d_in[5];
    const float* W1    = (const float*)d_in[6];
    const float* b1    = (const float*)d_in[7];
    const float* attl1 = (const float*)d_in[8];
    const float* attr1 = (const float*)d_in[9];
    const float* pW1   = (const float*)d_in[10];
    const float* pb1   = (const float*)d_in[11];
    const float* pW2   = (const float*)d_in[12];
    const float* pb2   = (const float*)d_in[13];

    const int* src = ei;
    const int* dst = ei + N_EDGES;

    float* out = (float*)d_out;          // [E]
    float* xo  = out + N_EDGES;          // [N,64] fp32 node output

    char* ws = (char*)d_ws;
    size_t o = 0;
    auto alloc = [&](size_t bytes) {
        char* p = ws + o;
        o = (o + bytes + 255) & ~(size_t)255;
        return p;
    };
    int*    deg  = (int*)alloc((size_t)N_NODES * 4);
    int*    off  = (int*)alloc((size_t)(N_NODES + 1) * 4);
    int*    cur  = (int*)alloc((size_t)N_NODES * 4);
    int*    esrc = (int*)alloc((size_t)N_EDGES * 4);
    int*    bsum = (int*)alloc(64 * 4);
    int*    boff = (int*)alloc(64 * 4);
    __half* hbuf = (__half*)alloc((size_t)N_NODES * HC * 2);
    float*  xbuf = (float*)alloc((size_t)N_NODES * HC * 4);
    __half* yh   = (__half*)alloc((size_t)N_NODES * OUTD * 2);
    float*  Wt0  = (float*)alloc((size_t)HC * HC * 4);
    float*  Wt1  = (float*)alloc((size_t)HC * HC * 4);
    float*  Wct  = (float*)alloc((size_t)HC * OUTD * 4);
    float*  bc   = (float*)alloc((size_t)OUTD * 4);
    (void)ws_size; (void)in_sizes; (void)n_in; (void)out_size;

    const int LIN_NB = (N_NODES + 31) / 32;        // 1563

    // fused CSR build + weight prep (cooperative: 49 blocks x 1024)
    {
        void* args[] = {
            (void*)&src, (void*)&dst, (void*)&deg, (void*)&off, (void*)&cur,
            (void*)&esrc, (void*)&bsum, (void*)&boff,
            (void*)&W0, (void*)&W1, (void*)&pW1, (void*)&pb1,
            (void*)&pW2, (void*)&pb2,
            (void*)&Wt0, (void*)&Wt1, (void*)&Wct, (void*)&bc,
        };
        hipLaunchCooperativeKernel((void*)k_csr, dim3(49), dim3(1024),
                                   args, 0, stream);
    }

    // GAT layer 0
    k_lin128<<<LIN_NB, 256, 0, stream>>>(emb, Wt0, b0, hbuf, N_NODES);
    k_gat_agg<<<(N_NODES + 3) / 4, 256, 0, stream>>>(hbuf, off, esrc, attl0, attr0,
                                                     xbuf, N_NODES, 0.01f);
    // GAT layer 1
    k_lin128<<<LIN_NB, 256, 0, stream>>>(xbuf, Wt1, b1, hbuf, N_NODES);
    k_gat_agg<<<(N_NODES + 3) / 4, 256, 0, stream>>>(hbuf, off, esrc, attl1, attr1,
                                                     xbuf, N_NODES, 0.01f);

    // post_mp (combined) + node output (fp32 + fp16 copy)
    k_lin64<<<LIN_NB, 256, 0, stream>>>(xbuf, Wct, bc, xo, yh, N_NODES);

    // edge scores
    k_edge_score<<<(N_EDGES * 8 + 255) / 256, 256, 0, stream>>>(yh, src, dst, out, N_EDGES);
}

// Round 7
// 300.482 us; speedup vs baseline: 1.1788x; 1.1788x over previous
//
#include <hip/hip_runtime.h>
#include <hip/hip_bf16.h>
#include <hip/hip_fp16.h>
#include <math.h>

#define N_NODES 50000
#define N_EDGES 800000
#define HC      128     // HEADS*HID
#define OUTD    64

// fast exp2: single v_exp_f32
#if defined(__has_builtin)
#if __has_builtin(__builtin_amdgcn_exp2f)
#define EXP2(x) __builtin_amdgcn_exp2f(x)
#endif
#endif
#ifndef EXP2
#define EXP2(x) __expf((x) * 0.69314718055994531f)
#endif

// ---------------- CSR build (separate wide kernels -- round 6's cooperative
// fusion collapsed edge-phase parallelism to 50K threads: occupancy 8%,
// 148us. Keep 800K-thread launches for the edge phases.) ----------------

__global__ void k_deg(const int* __restrict__ dst, int* __restrict__ deg, int e_cnt) {
    int e = blockIdx.x * blockDim.x + threadIdx.x;
    if (e < e_cnt) atomicAdd(&deg[dst[e]], 1);
}

// hierarchical scan: 49 blocks of 1024 -> 1 wave -> add-down
__global__ void k_scan_up(const int* __restrict__ deg, int* __restrict__ off,
                          int* __restrict__ bsum, int n) {
    __shared__ int wsum[16];
    __shared__ int wexc[16];
    const int lane = threadIdx.x & 63;
    const int wid  = threadIdx.x >> 6;
    int i = blockIdx.x * 1024 + threadIdx.x;
    int v = (i < n) ? deg[i] : 0;
    int incl = v;
    #pragma unroll
    for (int s = 1; s < 64; s <<= 1) {
        int t = __shfl_up(incl, s, 64);
        if (lane >= s) incl += t;
    }
    if (lane == 63) wsum[wid] = incl;
    __syncthreads();
    if (wid == 0 && lane < 16) {
        int w = wsum[lane];
        int wi = w;
        #pragma unroll
        for (int s = 1; s < 16; s <<= 1) {
            int t = __shfl_up(wi, s, 64);
            if (lane >= s) wi += t;
        }
        wexc[lane] = wi - w;
    }
    __syncthreads();
    int ex = wexc[wid] + incl - v;     // exclusive within block
    if (i < n) off[i] = ex;
    if (threadIdx.x == 1023) bsum[blockIdx.x] = ex + v;   // block total
}

__global__ void k_scan_mid(const int* __restrict__ bsum, int* __restrict__ boff,
                           int nb, int* __restrict__ off, int n) {
    int lane = threadIdx.x;   // 64 threads, nb <= 64
    int v = (lane < nb) ? bsum[lane] : 0;
    int incl = v;
    #pragma unroll
    for (int s = 1; s < 64; s <<= 1) {
        int t = __shfl_up(incl, s, 64);
        if (lane >= s) incl += t;
    }
    if (lane < nb) boff[lane] = incl - v;
    if (lane == 63) off[n] = incl;     // grand total
}

__global__ void k_scan_down(int* __restrict__ off, const int* __restrict__ boff,
                            int* __restrict__ cur, int n) {
    int i = blockIdx.x * 1024 + threadIdx.x;
    if (i < n) {
        int o = off[i] + boff[blockIdx.x];
        off[i] = o;
        cur[i] = o;
    }
}

__global__ void k_fill(const int* __restrict__ src, const int* __restrict__ dst,
                       int* __restrict__ cur, int* __restrict__ esrc, int e_cnt) {
    int e = blockIdx.x * blockDim.x + threadIdx.x;
    if (e < e_cnt) {
        int p = atomicAdd(&cur[dst[e]], 1);
        esrc[p] = src[e];
    }
}

// ---------------- weight prep (fused: 2 transposes + post_mp combine) ----------------

__global__ void k_prep(const float* __restrict__ W0, const float* __restrict__ W1,
                       const float* __restrict__ pW1, const float* __restrict__ pb1,
                       const float* __restrict__ pW2, const float* __restrict__ pb2,
                       float* __restrict__ Wt0, float* __restrict__ Wt1,
                       float* __restrict__ Wct, float* __restrict__ bc) {
    int i = blockIdx.x * blockDim.x + threadIdx.x;
    if (i < HC * HC) {
        int r = i >> 7, c = i & 127;
        Wt0[c * HC + r] = W0[i];
        Wt1[c * HC + r] = W1[i];
    } else if (i < HC * HC + HC * OUTD) {
        int j = i - HC * HC;
        int k = j >> 6, o2 = j & 63;
        float s = 0.f;
        for (int m = 0; m < 64; ++m) s += pW2[o2 * 64 + m] * pW1[m * 128 + k];
        Wct[k * 64 + o2] = s;
    } else if (i < HC * HC + HC * OUTD + OUTD) {
        int o2 = i - HC * HC - HC * OUTD;
        float s = pb2[o2];
        for (int m = 0; m < 64; ++m) s += pW2[o2 * 64 + m] * pb1[m];
        bc[o2] = s;
    }
}

// ---------------- linear: h = x @ Wt + b, K=128, OC=128, out fp16 ----------------
// LDS-staged weights. 32 nodes/block, Wt staged in two 32KB K-chunks,
// x staged once (16KB). 48KB LDS -> 3 blocks/CU.
// NOTE: macro params must not be named x/y/z/w (preprocessor substitutes
// member-access tokens -- round 3's compile failure).

#define FMA4(acc, wv, sv)                                                      \
    acc.x = fmaf(wv.x, sv, acc.x); acc.y = fmaf(wv.y, sv, acc.y);              \
    acc.z = fmaf(wv.z, sv, acc.z); acc.w = fmaf(wv.w, sv, acc.w);

__global__ __launch_bounds__(256) void k_lin128(const float* __restrict__ x,
                                                const float* __restrict__ Wt,
                                                const float* __restrict__ bias,
                                                __half* __restrict__ h, int n) {
    __shared__ float ws[64 * 128];      // 32KB: one K-chunk of Wt (rows = k)
    __shared__ float xs[32 * 128];      // 16KB: 32 node rows
    int t = threadIdx.x;
    int node0 = blockIdx.x * 32;
    for (int i = t; i < 1024; i += 256) {
        int row = i >> 5, c = i & 31;
        int gn = node0 + row;
        ((float4*)xs)[i] = (gn < n) ? ((const float4*)x)[(size_t)gn * 32 + c]
                                    : make_float4(0.f, 0.f, 0.f, 0.f);
    }
    int c4 = t & 31;                    // output float4 index [0,32)
    int ng = (t >> 5) * 4;              // first of my 4 nodes
    float4 bb = ((const float4*)bias)[c4];
    float4 a0 = bb, a1 = bb, a2 = bb, a3 = bb;
    const float4* xr0 = (const float4*)&xs[(ng + 0) * 128];
    const float4* xr1 = (const float4*)&xs[(ng + 1) * 128];
    const float4* xr2 = (const float4*)&xs[(ng + 2) * 128];
    const float4* xr3 = (const float4*)&xs[(ng + 3) * 128];

    for (int chunk = 0; chunk < 2; ++chunk) {
        __syncthreads();                // x ready (it=0) / ws no longer read (it=1)
        const float4* wsrc = (const float4*)&Wt[chunk * 64 * 128];
        for (int i = t; i < 2048; i += 256)
            ((float4*)ws)[i] = wsrc[i];
        __syncthreads();
        int kb = chunk * 16;
        #pragma unroll 4
        for (int k4 = 0; k4 < 16; ++k4) {
            float4 xv0 = xr0[kb + k4];
            float4 xv1 = xr1[kb + k4];
            float4 xv2 = xr2[kb + k4];
            float4 xv3 = xr3[kb + k4];
            const float* wr = &ws[k4 * 512];
            float4 w0 = ((const float4*)&wr[0])[c4];
            float4 w1 = ((const float4*)&wr[128])[c4];
            float4 w2 = ((const float4*)&wr[256])[c4];
            float4 w3 = ((const float4*)&wr[384])[c4];
            FMA4(a0, w0, xv0.x); FMA4(a0, w1, xv0.y); FMA4(a0, w2, xv0.z); FMA4(a0, w3, xv0.w);
            FMA4(a1, w0, xv1.x); FMA4(a1, w1, xv1.y); FMA4(a1, w2, xv1.z); FMA4(a1, w3, xv1.w);
            FMA4(a2, w0, xv2.x); FMA4(a2, w1, xv2.y); FMA4(a2, w2, xv2.z); FMA4(a2, w3, xv2.w);
            FMA4(a3, w0, xv3.x); FMA4(a3, w1, xv3.y); FMA4(a3, w2, xv3.z); FMA4(a3, w3, xv3.w);
        }
    }

    union { __half2 h2[2]; uint2 u; } p;
    int gn = node0 + ng;
    if (gn + 0 < n) { p.h2[0] = __floats2half2_rn(a0.x, a0.y); p.h2[1] = __floats2half2_rn(a0.z, a0.w);
                      *(uint2*)&h[(size_t)(gn + 0) * 128 + c4 * 4] = p.u; }
    if (gn + 1 < n) { p.h2[0] = __floats2half2_rn(a1.x, a1.y); p.h2[1] = __floats2half2_rn(a1.z, a1.w);
                      *(uint2*)&h[(size_t)(gn + 1) * 128 + c4 * 4] = p.u; }
    if (gn + 2 < n) { p.h2[0] = __floats2half2_rn(a2.x, a2.y); p.h2[1] = __floats2half2_rn(a2.z, a2.w);
                      *(uint2*)&h[(size_t)(gn + 2) * 128 + c4 * 4] = p.u; }
    if (gn + 3 < n) { p.h2[0] = __floats2half2_rn(a3.x, a3.y); p.h2[1] = __floats2half2_rn(a3.z, a3.w);
                      *(uint2*)&h[(size_t)(gn + 3) * 128 + c4 * 4] = p.u; }
}

// ---------------- GAT aggregate ----------------
// One wave per dst node, two half-waves by edge parity. Max-free log2-domain
// softmax (scores O(+-5), no overflow/flush possible; safety fallback below).
// Addressing diet: uniform SGPR h base + 32-bit voffset, strength-reduced
// shfl lane index (sl += 2), leaky via u = 0.2f*t.

__global__ __launch_bounds__(256) void k_gat_agg(const __half* __restrict__ h,
                                                 const int* __restrict__ off,
                                                 const int* __restrict__ esrc,
                                                 const float* __restrict__ attl,
                                                 const float* __restrict__ attr,
                                                 float* __restrict__ xout, int n,
                                                 float neg_out) {
    const float L2E = 1.4426950408889634f;
    int wid  = threadIdx.x >> 6;
    int lane = threadIdx.x & 63;
    int node = blockIdx.x * 4 + wid;
    if (node >= n) return;
    int half = lane >> 5;               // edge parity this half-wave owns
    int cq   = lane & 31;               // channel quad index
    uint32_t cq8 = (uint32_t)cq << 3;   // byte offset of my 4 fp16 channels

    const char* hb = (const char*)h;    // uniform base (SGPR) -- saddr form

    float4 alv = ((const float4*)attl)[cq];
    float4 arv = ((const float4*)attr)[cq];
    uint2 hdr = *(const uint2*)(hb + ((((uint32_t)node << 8)) | cq8));
    float2 hd01 = __half22float2(((const __half2*)&hdr)[0]);
    float2 hd23 = __half22float2(((const __half2*)&hdr)[1]);
    float al0 = alv.x * L2E, al1 = alv.y * L2E;
    float al2 = alv.z * L2E, al3 = alv.w * L2E;
    float ar0 = arv.x * hd01.x * L2E, ar1 = arv.y * hd01.y * L2E;
    float ar2 = arv.z * hd23.x * L2E, ar3 = arv.w * hd23.y * L2E;

    float z0 = 0.f, z1 = 0.f, z2 = 0.f, z3 = 0.f;
    float a0 = 0.f, a1 = 0.f, a2 = 0.f, a3 = 0.f;

    int beg = off[node], end = off[node + 1];

#define STEP(sAv)                                                              \
    {   uint32_t voff = (((uint32_t)(sAv)) << 8) | cq8;                        \
        uint2 hv = *(const uint2*)(hb + voff);                                 \
        float2 f01 = __half22float2(((const __half2*)&hv)[0]);                 \
        float2 f23 = __half22float2(((const __half2*)&hv)[1]);                 \
        float t0 = fmaf(al0, f01.x, ar0), t1 = fmaf(al1, f01.y, ar1);          \
        float t2 = fmaf(al2, f23.x, ar2), t3 = fmaf(al3, f23.y, ar3);          \
        float e0 = EXP2(fmaxf(t0, 0.2f * t0)), e1 = EXP2(fmaxf(t1, 0.2f * t1));\
        float e2 = EXP2(fmaxf(t2, 0.2f * t2)), e3 = EXP2(fmaxf(t3, 0.2f * t3));\
        z0 += e0; z1 += e1; z2 += e2; z3 += e3;                                \
        a0 = fmaf(e0, f01.x, a0); a1 = fmaf(e1, f01.y, a1);                    \
        a2 = fmaf(e2, f23.x, a2); a3 = fmaf(e3, f23.y, a3);                    \
    }

    for (int cbeg = beg; cbeg < end; cbeg += 64) {
        int cnt = end - cbeg; if (cnt > 64) cnt = 64;
        int myS = (cbeg + lane < end) ? esrc[cbeg + lane] : 0;
        int fullp = cnt >> 1;           // steps where both halves have an edge
        int sl = half;                  // strength-reduced shfl index
        #pragma unroll 4
        for (int t = 0; t < fullp; ++t) {
            int sA = __shfl(myS, sl, 64);   // all 64 lanes active
            sl += 2;
            STEP(sA);
        }
        if (cnt & 1) {                  // one leftover even-parity edge
            int sA = __shfl(myS, cnt - 1, 64);
            if (half == 0) STEP(sA);
        }
    }
#undef STEP

    // validity: overflow -> z inf/NaN; total underflow -> z==0 with edges
    float zs = z0 + z1 + z2 + z3;
    bool bad = !(zs < 3.0e38f);
    if (beg < end)
        bad = bad || !((z0 > 0.f) && (z1 > 0.f) && (z2 > 0.f) && (z3 > 0.f));

    if (__any(bad)) {
        // slow safe path (~never): two-pass max-shifted softmax; every lane
        // walks ALL edges, so both halves hold identical full sums (no merge).
        float m0 = -1e30f, m1 = -1e30f, m2 = -1e30f, m3 = -1e30f;
        for (int cbeg = beg; cbeg < end; cbeg += 64) {
            int cnt = end - cbeg; if (cnt > 64) cnt = 64;
            int myS = (cbeg + lane < end) ? esrc[cbeg + lane] : 0;
            for (int t = 0; t < cnt; ++t) {
                int sA = __shfl(myS, t, 64);
                uint2 hv = *(const uint2*)(hb + (((uint32_t)sA << 8) | cq8));
                float2 f01 = __half22float2(((const __half2*)&hv)[0]);
                float2 f23 = __half22float2(((const __half2*)&hv)[1]);
                float t0 = fmaf(al0, f01.x, ar0), t1 = fmaf(al1, f01.y, ar1);
                float t2 = fmaf(al2, f23.x, ar2), t3 = fmaf(al3, f23.y, ar3);
                m0 = fmaxf(m0, fmaxf(t0, 0.2f * t0));
                m1 = fmaxf(m1, fmaxf(t1, 0.2f * t1));
                m2 = fmaxf(m2, fmaxf(t2, 0.2f * t2));
                m3 = fmaxf(m3, fmaxf(t3, 0.2f * t3));
            }
        }
        z0 = z1 = z2 = z3 = 0.f;
        a0 = a1 = a2 = a3 = 0.f;
        for (int cbeg = beg; cbeg < end; cbeg += 64) {
            int cnt = end - cbeg; if (cnt > 64) cnt = 64;
            int myS = (cbeg + lane < end) ? esrc[cbeg + lane] : 0;
            for (int t = 0; t < cnt; ++t) {
                int sA = __shfl(myS, t, 64);
                uint2 hv = *(const uint2*)(hb + (((uint32_t)sA << 8) | cq8));
                float2 f01 = __half22float2(((const __half2*)&hv)[0]);
                float2 f23 = __half22float2(((const __half2*)&hv)[1]);
                float t0 = fmaf(al0, f01.x, ar0), t1 = fmaf(al1, f01.y, ar1);
                float t2 = fmaf(al2, f23.x, ar2), t3 = fmaf(al3, f23.y, ar3);
                float e0 = EXP2(fmaxf(t0, 0.2f * t0) - m0);
                float e1 = EXP2(fmaxf(t1, 0.2f * t1) - m1);
                float e2 = EXP2(fmaxf(t2, 0.2f * t2) - m2);
                float e3 = EXP2(fmaxf(t3, 0.2f * t3) - m3);
                z0 += e0; z1 += e1; z2 += e2; z3 += e3;
                a0 = fmaf(e0, f01.x, a0); a1 = fmaf(e1, f01.y, a1);
                a2 = fmaf(e2, f23.x, a2); a3 = fmaf(e3, f23.y, a3);
            }
        }
    } else {
        // merge parity halves: plain adds (shared implicit reference)
        z0 += __shfl_xor(z0, 32, 64); z1 += __shfl_xor(z1, 32, 64);
        z2 += __shfl_xor(z2, 32, 64); z3 += __shfl_xor(z3, 32, 64);
        a0 += __shfl_xor(a0, 32, 64); a1 += __shfl_xor(a1, 32, 64);
        a2 += __shfl_xor(a2, 32, 64); a3 += __shfl_xor(a3, 32, 64);
    }

    if (half == 0) {
        float o0 = (z0 > 0.f) ? a0 / z0 : 0.f;
        float o1 = (z1 > 0.f) ? a1 / z1 : 0.f;
        float o2 = (z2 > 0.f) ? a2 / z2 : 0.f;
        float o3 = (z3 > 0.f) ? a3 / z3 : 0.f;
        o0 = fmaxf(o0, neg_out * o0);
        o1 = fmaxf(o1, neg_out * o1);
        o2 = fmaxf(o2, neg_out * o2);
        o3 = fmaxf(o3, neg_out * o3);
        *(float4*)&xout[(size_t)node * 128 + cq * 4] = make_float4(o0, o1, o2, o3);
    }
}

// ---------------- final linear K=128 -> 64: LDS-staged Wct ----------------

__global__ __launch_bounds__(256) void k_lin64(const float* __restrict__ x,
                                               const float* __restrict__ Wct,
                                               const float* __restrict__ bc,
                                               float* __restrict__ y,
                                               __half* __restrict__ yh, int n) {
    __shared__ float ws[128 * 64];      // 32KB, row k: 64 outputs
    __shared__ float xs[32 * 128];      // 16KB
    int t = threadIdx.x;
    int node0 = blockIdx.x * 32;
    for (int i = t; i < 2048; i += 256)
        ((float4*)ws)[i] = ((const float4*)Wct)[i];
    for (int i = t; i < 1024; i += 256) {
        int row = i >> 5, c = i & 31;
        int gn = node0 + row;
        ((float4*)xs)[i] = (gn < n) ? ((const float4*)x)[(size_t)gn * 32 + c]
                                    : make_float4(0.f, 0.f, 0.f, 0.f);
    }
    __syncthreads();
    int l = t & 15;                     // output float4 index [0,16)
    int ng = (t >> 4) * 2;              // first of my 2 nodes
    float4 bb = ((const float4*)bc)[l];
    float4 a0 = bb, a1 = bb;
    const float4* xr0 = (const float4*)&xs[(ng + 0) * 128];
    const float4* xr1 = (const float4*)&xs[(ng + 1) * 128];
    #pragma unroll 4
    for (int k4 = 0; k4 < 32; ++k4) {
        float4 xv0 = xr0[k4];
        float4 xv1 = xr1[k4];
        const float* wr = &ws[k4 * 256];
        float4 w0 = ((const float4*)&wr[0])[l];
        float4 w1 = ((const float4*)&wr[64])[l];
        float4 w2 = ((const float4*)&wr[128])[l];
        float4 w3 = ((const float4*)&wr[192])[l];
        FMA4(a0, w0, xv0.x); FMA4(a0, w1, xv0.y); FMA4(a0, w2, xv0.z); FMA4(a0, w3, xv0.w);
        FMA4(a1, w0, xv1.x); FMA4(a1, w1, xv1.y); FMA4(a1, w2, xv1.z); FMA4(a1, w3, xv1.w);
    }
    union { __half2 h2[2]; uint2 u; } p;
    int gn = node0 + ng;
    if (gn + 0 < n) {
        ((float4*)&y[(size_t)(gn + 0) * 64])[l] = a0;
        p.h2[0] = __floats2half2_rn(a0.x, a0.y); p.h2[1] = __floats2half2_rn(a0.z, a0.w);
        *(uint2*)&yh[(size_t)(gn + 0) * 64 + l * 4] = p.u;
    }
    if (gn + 1 < n) {
        ((float4*)&y[(size_t)(gn + 1) * 64])[l] = a1;
        p.h2[0] = __floats2half2_rn(a1.x, a1.y); p.h2[1] = __floats2half2_rn(a1.z, a1.w);
        *(uint2*)&yh[(size_t)(gn + 1) * 64 + l * 4] = p.u;
    }
}

// ---------------- edge scores: sigmoid(dot(x[src], x[dst])), fp16 gather, 8 lanes/edge ----------------

__global__ __launch_bounds__(256) void k_edge_score(const __half* __restrict__ xh,
                                                    const int* __restrict__ src,
                                                    const int* __restrict__ dst,
                                                    float* __restrict__ out, int e_cnt) {
    int t = blockIdx.x * 256 + threadIdx.x;
    int e = t >> 3;
    int l = t & 7;
    if (e >= e_cnt) return;
    int u = src[e], v = dst[e];
    uint4 ua = ((const uint4*)&xh[(size_t)u * 64])[l];
    uint4 vb = ((const uint4*)&xh[(size_t)v * 64])[l];
    const __half2* pa = (const __half2*)&ua;
    const __half2* pb = (const __half2*)&vb;
    float d = 0.f;
    #pragma unroll
    for (int j = 0; j < 4; ++j) {
        float2 fa = __half22float2(pa[j]);
        float2 fb = __half22float2(pb[j]);
        d = fmaf(fa.x, fb.x, d);
        d = fmaf(fa.y, fb.y, d);
    }
    d += __shfl_xor(d, 1);
    d += __shfl_xor(d, 2);
    d += __shfl_xor(d, 4);
    if (l == 0) out[e] = 1.f / (1.f + __expf(-d));
}

// ---------------- launch ----------------

extern "C" void kernel_launch(void* const* d_in, const int* in_sizes, int n_in,
                              void* d_out, int out_size, void* d_ws, size_t ws_size,
                              hipStream_t stream) {
    const float* emb   = (const float*)d_in[0];
    const int*   ei    = (const int*)d_in[1];
    const float* W0    = (const float*)d_in[2];
    const float* b0    = (const float*)d_in[3];
    const float* attl0 = (const float*)d_in[4];
    const float* attr0 = (const float*)d_in[5];
    const float* W1    = (const float*)d_in[6];
    const float* b1    = (const float*)d_in[7];
    const float* attl1 = (const float*)d_in[8];
    const float* attr1 = (const float*)d_in[9];
    const float* pW1   = (const float*)d_in[10];
    const float* pb1   = (const float*)d_in[11];
    const float* pW2   = (const float*)d_in[12];
    const float* pb2   = (const float*)d_in[13];

    const int* src = ei;
    const int* dst = ei + N_EDGES;

    float* out = (float*)d_out;          // [E]
    float* xo  = out + N_EDGES;          // [N,64] fp32 node output

    char* ws = (char*)d_ws;
    size_t o = 0;
    auto alloc = [&](size_t bytes) {
        char* p = ws + o;
        o = (o + bytes + 255) & ~(size_t)255;
        return p;
    };
    int*    deg  = (int*)alloc((size_t)N_NODES * 4);
    int*    off  = (int*)alloc((size_t)(N_NODES + 1) * 4);
    int*    cur  = (int*)alloc((size_t)N_NODES * 4);
    int*    esrc = (int*)alloc((size_t)N_EDGES * 4);
    int*    bsum = (int*)alloc(64 * 4);
    int*    boff = (int*)alloc(64 * 4);
    __half* hbuf = (__half*)alloc((size_t)N_NODES * HC * 2);
    float*  xbuf = (float*)alloc((size_t)N_NODES * HC * 4);
    __half* yh   = (__half*)alloc((size_t)N_NODES * OUTD * 2);
    float*  Wt0  = (float*)alloc((size_t)HC * HC * 4);
    float*  Wt1  = (float*)alloc((size_t)HC * HC * 4);
    float*  Wct  = (float*)alloc((size_t)HC * OUTD * 4);
    float*  bc   = (float*)alloc((size_t)OUTD * 4);
    (void)ws_size; (void)in_sizes; (void)n_in; (void)out_size;

    const int SCAN_NB = (N_NODES + 1023) / 1024;   // 49
    const int LIN_NB  = (N_NODES + 31) / 32;       // 1563
    const int PREP_N  = HC * HC + HC * OUTD + OUTD;

    // weight prep (independent of everything else)
    k_prep<<<(PREP_N + 255) / 256, 256, 0, stream>>>(W0, W1, pW1, pb1, pW2, pb2,
                                                     Wt0, Wt1, Wct, bc);

    // CSR by dst (wide launches: full edge parallelism)
    hipMemsetAsync(deg, 0, (size_t)N_NODES * 4, stream);
    k_deg <<<(N_EDGES + 255) / 256, 256, 0, stream>>>(dst, deg, N_EDGES);
    k_scan_up  <<<SCAN_NB, 1024, 0, stream>>>(deg, off, bsum, N_NODES);
    k_scan_mid <<<1, 64, 0, stream>>>(bsum, boff, SCAN_NB, off, N_NODES);
    k_scan_down<<<SCAN_NB, 1024, 0, stream>>>(off, boff, cur, N_NODES);
    k_fill<<<(N_EDGES + 255) / 256, 256, 0, stream>>>(src, dst, cur, esrc, N_EDGES);

    // GAT layer 0
    k_lin128<<<LIN_NB, 256, 0, stream>>>(emb, Wt0, b0, hbuf, N_NODES);
    k_gat_agg<<<(N_NODES + 3) / 4, 256, 0, stream>>>(hbuf, off, esrc, attl0, attr0,
                                                     xbuf, N_NODES, 0.01f);
    // GAT layer 1
    k_lin128<<<LIN_NB, 256, 0, stream>>>(xbuf, Wt1, b1, hbuf, N_NODES);
    k_gat_agg<<<(N_NODES + 3) / 4, 256, 0, stream>>>(hbuf, off, esrc, attl1, attr1,
                                                     xbuf, N_NODES, 0.01f);

    // post_mp (combined) + node output (fp32 + fp16 copy)
    k_lin64<<<LIN_NB, 256, 0, stream>>>(xbuf, Wct, bc, xo, yh, N_NODES);

    // edge scores
    k_edge_score<<<(N_EDGES * 8 + 255) / 256, 256, 0, stream>>>(yh, src, dst, out, N_EDGES);
}

// Round 8
// 240.284 us; speedup vs baseline: 1.4741x; 1.2505x over previous
//
#include <hip/hip_runtime.h>
#include <hip/hip_bf16.h>
#include <hip/hip_fp16.h>
#include <math.h>

#define N_NODES 50000
#define N_EDGES 800000
#define HC      128     // HEADS*HID
#define OUTD    64
#define NBKT    ((N_NODES + 63) / 64)   // 782 buckets of 64 nodes

// fast exp2: single v_exp_f32
#if defined(__has_builtin)
#if __has_builtin(__builtin_amdgcn_exp2f)
#define EXP2(x) __builtin_amdgcn_exp2f(x)
#endif
#endif
#ifndef EXP2
#define EXP2(x) __expf((x) * 0.69314718055994531f)
#endif

// ---------------- bucketed CSR build ----------------
// Round 7 pmc: k_fill WRITE_SIZE = 51.6MB for 3.2MB payload (64B/edge, 16x
// write amplification -- random 4B scatter, L2 can't combine). Fix: bucket
// edges by dst>>6 first (write runs are per-(block,bucket) contiguous), then
// finalize per-bucket with LDS counters (esrc region per bucket = contiguous
// 4KB written by one block). Also kills k_deg + 3 scan kernels: off[] comes
// from bucket base + in-bucket LDS scan.

__global__ __launch_bounds__(1024) void k_hist(const int* __restrict__ dst,
                                               int* __restrict__ bcnt, int e_cnt) {
    __shared__ int lh[NBKT];
    for (int i = threadIdx.x; i < NBKT; i += 1024) lh[i] = 0;
    __syncthreads();
    int base = blockIdx.x * 8192;
    for (int i = threadIdx.x; i < 8192; i += 1024) {
        int e = base + i;
        if (e < e_cnt) atomicAdd(&lh[dst[e] >> 6], 1);
    }
    __syncthreads();
    for (int i = threadIdx.x; i < NBKT; i += 1024) {
        int c = lh[i];
        if (c) atomicAdd(&bcnt[i], c);
    }
}

__global__ __launch_bounds__(1024) void k_bscan(const int* __restrict__ bcnt,
                                                int* __restrict__ bbase,
                                                int* __restrict__ bcur) {
    __shared__ int wsum[16];
    __shared__ int wexc[16];
    int t = threadIdx.x, lane = t & 63, wid = t >> 6;
    int v = (t < NBKT) ? bcnt[t] : 0;
    int incl = v;
    #pragma unroll
    for (int s = 1; s < 64; s <<= 1) {
        int u = __shfl_up(incl, s, 64);
        if (lane >= s) incl += u;
    }
    if (lane == 63) wsum[wid] = incl;
    __syncthreads();
    if (wid == 0 && lane < 16) {
        int w = wsum[lane];
        int wi = w;
        #pragma unroll
        for (int s = 1; s < 16; s <<= 1) {
            int u = __shfl_up(wi, s, 64);
            if (lane >= s) wi += u;
        }
        wexc[lane] = wi - w;
    }
    __syncthreads();
    int ex = wexc[wid] + incl - v;
    if (t < NBKT) { bbase[t] = ex; bcur[t] = ex; }
    if (t == NBKT - 1) bbase[NBKT] = ex + v;   // == e_cnt
}

__global__ __launch_bounds__(1024) void k_bscatter(const int* __restrict__ src,
                                                   const int* __restrict__ dst,
                                                   int* __restrict__ bcur,
                                                   uint2* __restrict__ ebuf, int e_cnt) {
    __shared__ int lcnt[NBKT];
    __shared__ int lbase[NBKT];
    for (int i = threadIdx.x; i < NBKT; i += 1024) lcnt[i] = 0;
    __syncthreads();
    int base = blockIdx.x * 8192;
    int myS[8], myD[8], myR[8];
    #pragma unroll
    for (int j = 0; j < 8; ++j) {
        int e = base + threadIdx.x + j * 1024;          // coalesced
        if (e < e_cnt) {
            myS[j] = src[e];
            myD[j] = dst[e];
            myR[j] = atomicAdd(&lcnt[myD[j] >> 6], 1);  // LDS rank (fast)
        } else myD[j] = -1;
    }
    __syncthreads();
    for (int i = threadIdx.x; i < NBKT; i += 1024) {
        int c = lcnt[i];
        lbase[i] = c ? atomicAdd(&bcur[i], c) : 0;      // reserve range once
    }
    __syncthreads();
    #pragma unroll
    for (int j = 0; j < 8; ++j) {
        if (myD[j] >= 0) {
            int bkt = myD[j] >> 6;
            ebuf[lbase[bkt] + myR[j]] =
                make_uint2((unsigned)myS[j], (unsigned)myD[j]);
        }
    }
}

__global__ __launch_bounds__(256) void k_bfinal(const uint2* __restrict__ ebuf,
                                                const int* __restrict__ bbase,
                                                int* __restrict__ off,
                                                int* __restrict__ esrc, int n) {
    __shared__ int ncnt[64];
    __shared__ int ncur[64];
    int b = blockIdx.x;
    int t = threadIdx.x;
    int ebeg = bbase[b], eend = bbase[b + 1];
    if (t < 64) ncnt[t] = 0;
    __syncthreads();
    for (int e = ebeg + t; e < eend; e += 256)
        atomicAdd(&ncnt[ebuf[e].y & 63], 1);
    __syncthreads();
    if (t < 64) {
        int v = ncnt[t];
        int incl = v;
        #pragma unroll
        for (int s = 1; s < 64; s <<= 1) {
            int u = __shfl_up(incl, s, 64);
            if (t >= s) incl += u;
        }
        int ex = incl - v;
        ncur[t] = ex;
        int node = b * 64 + t;
        if (node <= n) off[node] = ebeg + ex;   // covers off[n] via last bucket
    }
    __syncthreads();
    for (int e = ebeg + t; e < eend; e += 256) {
        uint2 ed = ebuf[e];
        int r = atomicAdd(&ncur[ed.y & 63], 1);
        esrc[ebeg + r] = (int)ed.x;             // contiguous 4KB region per block
    }
}

// ---------------- weight prep (fused: 2 transposes + post_mp combine) ----------------

__global__ void k_prep(const float* __restrict__ W0, const float* __restrict__ W1,
                       const float* __restrict__ pW1, const float* __restrict__ pb1,
                       const float* __restrict__ pW2, const float* __restrict__ pb2,
                       float* __restrict__ Wt0, float* __restrict__ Wt1,
                       float* __restrict__ Wct, float* __restrict__ bc) {
    int i = blockIdx.x * blockDim.x + threadIdx.x;
    if (i < HC * HC) {
        int r = i >> 7, c = i & 127;
        Wt0[c * HC + r] = W0[i];
        Wt1[c * HC + r] = W1[i];
    } else if (i < HC * HC + HC * OUTD) {
        int j = i - HC * HC;
        int k = j >> 6, o2 = j & 63;
        float s = 0.f;
        for (int m = 0; m < 64; ++m) s += pW2[o2 * 64 + m] * pW1[m * 128 + k];
        Wct[k * 64 + o2] = s;
    } else if (i < HC * HC + HC * OUTD + OUTD) {
        int o2 = i - HC * HC - HC * OUTD;
        float s = pb2[o2];
        for (int m = 0; m < 64; ++m) s += pW2[o2 * 64 + m] * pb1[m];
        bc[o2] = s;
    }
}

// ---------------- linear: h = x @ Wt + b, K=128, OC=128, out fp16 ----------------
// NOTE: macro params must not be named x/y/z/w (preprocessor substitutes
// member-access tokens -- round 3's compile failure).

#define FMA4(acc, wv, sv)                                                      \
    acc.x = fmaf(wv.x, sv, acc.x); acc.y = fmaf(wv.y, sv, acc.y);              \
    acc.z = fmaf(wv.z, sv, acc.z); acc.w = fmaf(wv.w, sv, acc.w);

__global__ __launch_bounds__(256) void k_lin128(const float* __restrict__ x,
                                                const float* __restrict__ Wt,
                                                const float* __restrict__ bias,
                                                __half* __restrict__ h, int n) {
    __shared__ float ws[64 * 128];      // 32KB: one K-chunk of Wt (rows = k)
    __shared__ float xs[32 * 128];      // 16KB: 32 node rows
    int t = threadIdx.x;
    int node0 = blockIdx.x * 32;
    for (int i = t; i < 1024; i += 256) {
        int row = i >> 5, c = i & 31;
        int gn = node0 + row;
        ((float4*)xs)[i] = (gn < n) ? ((const float4*)x)[(size_t)gn * 32 + c]
                                    : make_float4(0.f, 0.f, 0.f, 0.f);
    }
    int c4 = t & 31;                    // output float4 index [0,32)
    int ng = (t >> 5) * 4;              // first of my 4 nodes
    float4 bb = ((const float4*)bias)[c4];
    float4 a0 = bb, a1 = bb, a2 = bb, a3 = bb;
    const float4* xr0 = (const float4*)&xs[(ng + 0) * 128];
    const float4* xr1 = (const float4*)&xs[(ng + 1) * 128];
    const float4* xr2 = (const float4*)&xs[(ng + 2) * 128];
    const float4* xr3 = (const float4*)&xs[(ng + 3) * 128];

    for (int chunk = 0; chunk < 2; ++chunk) {
        __syncthreads();
        const float4* wsrc = (const float4*)&Wt[chunk * 64 * 128];
        for (int i = t; i < 2048; i += 256)
            ((float4*)ws)[i] = wsrc[i];
        __syncthreads();
        int kb = chunk * 16;
        #pragma unroll 4
        for (int k4 = 0; k4 < 16; ++k4) {
            float4 xv0 = xr0[kb + k4];
            float4 xv1 = xr1[kb + k4];
            float4 xv2 = xr2[kb + k4];
            float4 xv3 = xr3[kb + k4];
            const float* wr = &ws[k4 * 512];
            float4 w0 = ((const float4*)&wr[0])[c4];
            float4 w1 = ((const float4*)&wr[128])[c4];
            float4 w2 = ((const float4*)&wr[256])[c4];
            float4 w3 = ((const float4*)&wr[384])[c4];
            FMA4(a0, w0, xv0.x); FMA4(a0, w1, xv0.y); FMA4(a0, w2, xv0.z); FMA4(a0, w3, xv0.w);
            FMA4(a1, w0, xv1.x); FMA4(a1, w1, xv1.y); FMA4(a1, w2, xv1.z); FMA4(a1, w3, xv1.w);
            FMA4(a2, w0, xv2.x); FMA4(a2, w1, xv2.y); FMA4(a2, w2, xv2.z); FMA4(a2, w3, xv2.w);
            FMA4(a3, w0, xv3.x); FMA4(a3, w1, xv3.y); FMA4(a3, w2, xv3.z); FMA4(a3, w3, xv3.w);
        }
    }

    union { __half2 h2[2]; uint2 u; } p;
    int gn = node0 + ng;
    if (gn + 0 < n) { p.h2[0] = __floats2half2_rn(a0.x, a0.y); p.h2[1] = __floats2half2_rn(a0.z, a0.w);
                      *(uint2*)&h[(size_t)(gn + 0) * 128 + c4 * 4] = p.u; }
    if (gn + 1 < n) { p.h2[0] = __floats2half2_rn(a1.x, a1.y); p.h2[1] = __floats2half2_rn(a1.z, a1.w);
                      *(uint2*)&h[(size_t)(gn + 1) * 128 + c4 * 4] = p.u; }
    if (gn + 2 < n) { p.h2[0] = __floats2half2_rn(a2.x, a2.y); p.h2[1] = __floats2half2_rn(a2.z, a2.w);
                      *(uint2*)&h[(size_t)(gn + 2) * 128 + c4 * 4] = p.u; }
    if (gn + 3 < n) { p.h2[0] = __floats2half2_rn(a3.x, a3.y); p.h2[1] = __floats2half2_rn(a3.z, a3.w);
                      *(uint2*)&h[(size_t)(gn + 3) * 128 + c4 * 4] = p.u; }
}

// ---------------- GAT aggregate (unchanged from round 7) ----------------

__global__ __launch_bounds__(256) void k_gat_agg(const __half* __restrict__ h,
                                                 const int* __restrict__ off,
                                                 const int* __restrict__ esrc,
                                                 const float* __restrict__ attl,
                                                 const float* __restrict__ attr,
                                                 float* __restrict__ xout, int n,
                                                 float neg_out) {
    const float L2E = 1.4426950408889634f;
    int wid  = threadIdx.x >> 6;
    int lane = threadIdx.x & 63;
    int node = blockIdx.x * 4 + wid;
    if (node >= n) return;
    int half = lane >> 5;               // edge parity this half-wave owns
    int cq   = lane & 31;               // channel quad index
    uint32_t cq8 = (uint32_t)cq << 3;   // byte offset of my 4 fp16 channels

    const char* hb = (const char*)h;    // uniform base (SGPR) -- saddr form

    float4 alv = ((const float4*)attl)[cq];
    float4 arv = ((const float4*)attr)[cq];
    uint2 hdr = *(const uint2*)(hb + ((((uint32_t)node << 8)) | cq8));
    float2 hd01 = __half22float2(((const __half2*)&hdr)[0]);
    float2 hd23 = __half22float2(((const __half2*)&hdr)[1]);
    float al0 = alv.x * L2E, al1 = alv.y * L2E;
    float al2 = alv.z * L2E, al3 = alv.w * L2E;
    float ar0 = arv.x * hd01.x * L2E, ar1 = arv.y * hd01.y * L2E;
    float ar2 = arv.z * hd23.x * L2E, ar3 = arv.w * hd23.y * L2E;

    float z0 = 0.f, z1 = 0.f, z2 = 0.f, z3 = 0.f;
    float a0 = 0.f, a1 = 0.f, a2 = 0.f, a3 = 0.f;

    int beg = off[node], end = off[node + 1];

#define STEP(sAv)                                                              \
    {   uint32_t voff = (((uint32_t)(sAv)) << 8) | cq8;                        \
        uint2 hv = *(const uint2*)(hb + voff);                                 \
        float2 f01 = __half22float2(((const __half2*)&hv)[0]);                 \
        float2 f23 = __half22float2(((const __half2*)&hv)[1]);                 \
        float t0 = fmaf(al0, f01.x, ar0), t1 = fmaf(al1, f01.y, ar1);          \
        float t2 = fmaf(al2, f23.x, ar2), t3 = fmaf(al3, f23.y, ar3);          \
        float e0 = EXP2(fmaxf(t0, 0.2f * t0)), e1 = EXP2(fmaxf(t1, 0.2f * t1));\
        float e2 = EXP2(fmaxf(t2, 0.2f * t2)), e3 = EXP2(fmaxf(t3, 0.2f * t3));\
        z0 += e0; z1 += e1; z2 += e2; z3 += e3;                                \
        a0 = fmaf(e0, f01.x, a0); a1 = fmaf(e1, f01.y, a1);                    \
        a2 = fmaf(e2, f23.x, a2); a3 = fmaf(e3, f23.y, a3);                    \
    }

    for (int cbeg = beg; cbeg < end; cbeg += 64) {
        int cnt = end - cbeg; if (cnt > 64) cnt = 64;
        int myS = (cbeg + lane < end) ? esrc[cbeg + lane] : 0;
        int fullp = cnt >> 1;           // steps where both halves have an edge
        int sl = half;                  // strength-reduced shfl index
        #pragma unroll 4
        for (int t = 0; t < fullp; ++t) {
            int sA = __shfl(myS, sl, 64);   // all 64 lanes active
            sl += 2;
            STEP(sA);
        }
        if (cnt & 1) {                  // one leftover even-parity edge
            int sA = __shfl(myS, cnt - 1, 64);
            if (half == 0) STEP(sA);
        }
    }
#undef STEP

    // validity: overflow -> z inf/NaN; total underflow -> z==0 with edges
    float zs = z0 + z1 + z2 + z3;
    bool bad = !(zs < 3.0e38f);
    if (beg < end)
        bad = bad || !((z0 > 0.f) && (z1 > 0.f) && (z2 > 0.f) && (z3 > 0.f));

    if (__any(bad)) {
        // slow safe path (~never): two-pass max-shifted softmax; every lane
        // walks ALL edges, so both halves hold identical full sums (no merge).
        float m0 = -1e30f, m1 = -1e30f, m2 = -1e30f, m3 = -1e30f;
        for (int cbeg = beg; cbeg < end; cbeg += 64) {
            int cnt = end - cbeg; if (cnt > 64) cnt = 64;
            int myS = (cbeg + lane < end) ? esrc[cbeg + lane] : 0;
            for (int t = 0; t < cnt; ++t) {
                int sA = __shfl(myS, t, 64);
                uint2 hv = *(const uint2*)(hb + (((uint32_t)sA << 8) | cq8));
                float2 f01 = __half22float2(((const __half2*)&hv)[0]);
                float2 f23 = __half22float2(((const __half2*)&hv)[1]);
                float t0 = fmaf(al0, f01.x, ar0), t1 = fmaf(al1, f01.y, ar1);
                float t2 = fmaf(al2, f23.x, ar2), t3 = fmaf(al3, f23.y, ar3);
                m0 = fmaxf(m0, fmaxf(t0, 0.2f * t0));
                m1 = fmaxf(m1, fmaxf(t1, 0.2f * t1));
                m2 = fmaxf(m2, fmaxf(t2, 0.2f * t2));
                m3 = fmaxf(m3, fmaxf(t3, 0.2f * t3));
            }
        }
        z0 = z1 = z2 = z3 = 0.f;
        a0 = a1 = a2 = a3 = 0.f;
        for (int cbeg = beg; cbeg < end; cbeg += 64) {
            int cnt = end - cbeg; if (cnt > 64) cnt = 64;
            int myS = (cbeg + lane < end) ? esrc[cbeg + lane] : 0;
            for (int t = 0; t < cnt; ++t) {
                int sA = __shfl(myS, t, 64);
                uint2 hv = *(const uint2*)(hb + (((uint32_t)sA << 8) | cq8));
                float2 f01 = __half22float2(((const __half2*)&hv)[0]);
                float2 f23 = __half22float2(((const __half2*)&hv)[1]);
                float t0 = fmaf(al0, f01.x, ar0), t1 = fmaf(al1, f01.y, ar1);
                float t2 = fmaf(al2, f23.x, ar2), t3 = fmaf(al3, f23.y, ar3);
                float e0 = EXP2(fmaxf(t0, 0.2f * t0) - m0);
                float e1 = EXP2(fmaxf(t1, 0.2f * t1) - m1);
                float e2 = EXP2(fmaxf(t2, 0.2f * t2) - m2);
                float e3 = EXP2(fmaxf(t3, 0.2f * t3) - m3);
                z0 += e0; z1 += e1; z2 += e2; z3 += e3;
                a0 = fmaf(e0, f01.x, a0); a1 = fmaf(e1, f01.y, a1);
                a2 = fmaf(e2, f23.x, a2); a3 = fmaf(e3, f23.y, a3);
            }
        }
    } else {
        // merge parity halves: plain adds (shared implicit reference)
        z0 += __shfl_xor(z0, 32, 64); z1 += __shfl_xor(z1, 32, 64);
        z2 += __shfl_xor(z2, 32, 64); z3 += __shfl_xor(z3, 32, 64);
        a0 += __shfl_xor(a0, 32, 64); a1 += __shfl_xor(a1, 32, 64);
        a2 += __shfl_xor(a2, 32, 64); a3 += __shfl_xor(a3, 32, 64);
    }

    if (half == 0) {
        float o0 = (z0 > 0.f) ? a0 / z0 : 0.f;
        float o1 = (z1 > 0.f) ? a1 / z1 : 0.f;
        float o2 = (z2 > 0.f) ? a2 / z2 : 0.f;
        float o3 = (z3 > 0.f) ? a3 / z3 : 0.f;
        o0 = fmaxf(o0, neg_out * o0);
        o1 = fmaxf(o1, neg_out * o1);
        o2 = fmaxf(o2, neg_out * o2);
        o3 = fmaxf(o3, neg_out * o3);
        *(float4*)&xout[(size_t)node * 128 + cq * 4] = make_float4(o0, o1, o2, o3);
    }
}

// ---------------- final linear K=128 -> 64: LDS-staged Wct ----------------

__global__ __launch_bounds__(256) void k_lin64(const float* __restrict__ x,
                                               const float* __restrict__ Wct,
                                               const float* __restrict__ bc,
                                               float* __restrict__ y,
                                               __half* __restrict__ yh, int n) {
    __shared__ float ws[128 * 64];      // 32KB, row k: 64 outputs
    __shared__ float xs[32 * 128];      // 16KB
    int t = threadIdx.x;
    int node0 = blockIdx.x * 32;
    for (int i = t; i < 2048; i += 256)
        ((float4*)ws)[i] = ((const float4*)Wct)[i];
    for (int i = t; i < 1024; i += 256) {
        int row = i >> 5, c = i & 31;
        int gn = node0 + row;
        ((float4*)xs)[i] = (gn < n) ? ((const float4*)x)[(size_t)gn * 32 + c]
                                    : make_float4(0.f, 0.f, 0.f, 0.f);
    }
    __syncthreads();
    int l = t & 15;                     // output float4 index [0,16)
    int ng = (t >> 4) * 2;              // first of my 2 nodes
    float4 bb = ((const float4*)bc)[l];
    float4 a0 = bb, a1 = bb;
    const float4* xr0 = (const float4*)&xs[(ng + 0) * 128];
    const float4* xr1 = (const float4*)&xs[(ng + 1) * 128];
    #pragma unroll 4
    for (int k4 = 0; k4 < 32; ++k4) {
        float4 xv0 = xr0[k4];
        float4 xv1 = xr1[k4];
        const float* wr = &ws[k4 * 256];
        float4 w0 = ((const float4*)&wr[0])[l];
        float4 w1 = ((const float4*)&wr[64])[l];
        float4 w2 = ((const float4*)&wr[128])[l];
        float4 w3 = ((const float4*)&wr[192])[l];
        FMA4(a0, w0, xv0.x); FMA4(a0, w1, xv0.y); FMA4(a0, w2, xv0.z); FMA4(a0, w3, xv0.w);
        FMA4(a1, w0, xv1.x); FMA4(a1, w1, xv1.y); FMA4(a1, w2, xv1.z); FMA4(a1, w3, xv1.w);
    }
    union { __half2 h2[2]; uint2 u; } p;
    int gn = node0 + ng;
    if (gn + 0 < n) {
        ((float4*)&y[(size_t)(gn + 0) * 64])[l] = a0;
        p.h2[0] = __floats2half2_rn(a0.x, a0.y); p.h2[1] = __floats2half2_rn(a0.z, a0.w);
        *(uint2*)&yh[(size_t)(gn + 0) * 64 + l * 4] = p.u;
    }
    if (gn + 1 < n) {
        ((float4*)&y[(size_t)(gn + 1) * 64])[l] = a1;
        p.h2[0] = __floats2half2_rn(a1.x, a1.y); p.h2[1] = __floats2half2_rn(a1.z, a1.w);
        *(uint2*)&yh[(size_t)(gn + 1) * 64 + l * 4] = p.u;
    }
}

// ---------------- edge scores: sigmoid(dot(x[src], x[dst])), fp16 gather, 8 lanes/edge ----------------

__global__ __launch_bounds__(256) void k_edge_score(const __half* __restrict__ xh,
                                                    const int* __restrict__ src,
                                                    const int* __restrict__ dst,
                                                    float* __restrict__ out, int e_cnt) {
    int t = blockIdx.x * 256 + threadIdx.x;
    int e = t >> 3;
    int l = t & 7;
    if (e >= e_cnt) return;
    int u = src[e], v = dst[e];
    uint4 ua = ((const uint4*)&xh[(size_t)u * 64])[l];
    uint4 vb = ((const uint4*)&xh[(size_t)v * 64])[l];
    const __half2* pa = (const __half2*)&ua;
    const __half2* pb = (const __half2*)&vb;
    float d = 0.f;
    #pragma unroll
    for (int j = 0; j < 4; ++j) {
        float2 fa = __half22float2(pa[j]);
        float2 fb = __half22float2(pb[j]);
        d = fmaf(fa.x, fb.x, d);
        d = fmaf(fa.y, fb.y, d);
    }
    d += __shfl_xor(d, 1);
    d += __shfl_xor(d, 2);
    d += __shfl_xor(d, 4);
    if (l == 0) out[e] = 1.f / (1.f + __expf(-d));
}

// ---------------- launch ----------------

extern "C" void kernel_launch(void* const* d_in, const int* in_sizes, int n_in,
                              void* d_out, int out_size, void* d_ws, size_t ws_size,
                              hipStream_t stream) {
    const float* emb   = (const float*)d_in[0];
    const int*   ei    = (const int*)d_in[1];
    const float* W0    = (const float*)d_in[2];
    const float* b0    = (const float*)d_in[3];
    const float* attl0 = (const float*)d_in[4];
    const float* attr0 = (const float*)d_in[5];
    const float* W1    = (const float*)d_in[6];
    const float* b1    = (const float*)d_in[7];
    const float* attl1 = (const float*)d_in[8];
    const float* attr1 = (const float*)d_in[9];
    const float* pW1   = (const float*)d_in[10];
    const float* pb1   = (const float*)d_in[11];
    const float* pW2   = (const float*)d_in[12];
    const float* pb2   = (const float*)d_in[13];

    const int* src = ei;
    const int* dst = ei + N_EDGES;

    float* out = (float*)d_out;          // [E]
    float* xo  = out + N_EDGES;          // [N,64] fp32 node output

    char* ws = (char*)d_ws;
    size_t o = 0;
    auto alloc = [&](size_t bytes) {
        char* p = ws + o;
        o = (o + bytes + 255) & ~(size_t)255;
        return p;
    };
    int*    off   = (int*)alloc((size_t)(N_NODES + 1) * 4);
    int*    esrc  = (int*)alloc((size_t)N_EDGES * 4);
    int*    bcnt  = (int*)alloc((size_t)(NBKT + 1) * 4);
    int*    bbase = (int*)alloc((size_t)(NBKT + 1) * 4);
    int*    bcur  = (int*)alloc((size_t)(NBKT + 1) * 4);
    uint2*  ebuf  = (uint2*)alloc((size_t)N_EDGES * 8);
    __half* hbuf  = (__half*)alloc((size_t)N_NODES * HC * 2);
    float*  xbuf  = (float*)alloc((size_t)N_NODES * HC * 4);
    __half* yh    = (__half*)alloc((size_t)N_NODES * OUTD * 2);
    float*  Wt0   = (float*)alloc((size_t)HC * HC * 4);
    float*  Wt1   = (float*)alloc((size_t)HC * HC * 4);
    float*  Wct   = (float*)alloc((size_t)HC * OUTD * 4);
    float*  bc    = (float*)alloc((size_t)OUTD * 4);
    (void)ws_size; (void)in_sizes; (void)n_in; (void)out_size;

    const int LIN_NB = (N_NODES + 31) / 32;        // 1563
    const int EB_NB  = (N_EDGES + 8191) / 8192;    // 98
    const int PREP_N = HC * HC + HC * OUTD + OUTD;

    // weight prep (independent of everything else)
    k_prep<<<(PREP_N + 255) / 256, 256, 0, stream>>>(W0, W1, pW1, pb1, pW2, pb2,
                                                     Wt0, Wt1, Wct, bc);

    // bucketed CSR build
    hipMemsetAsync(bcnt, 0, (size_t)(NBKT + 1) * 4, stream);
    k_hist    <<<EB_NB, 1024, 0, stream>>>(dst, bcnt, N_EDGES);
    k_bscan   <<<1, 1024, 0, stream>>>(bcnt, bbase, bcur);
    k_bscatter<<<EB_NB, 1024, 0, stream>>>(src, dst, bcur, ebuf, N_EDGES);
    k_bfinal  <<<NBKT, 256, 0, stream>>>(ebuf, bbase, off, esrc, N_NODES);

    // GAT layer 0
    k_lin128<<<LIN_NB, 256, 0, stream>>>(emb, Wt0, b0, hbuf, N_NODES);
    k_gat_agg<<<(N_NODES + 3) / 4, 256, 0, stream>>>(hbuf, off, esrc, attl0, attr0,
                                                     xbuf, N_NODES, 0.01f);
    // GAT layer 1
    k_lin128<<<LIN_NB, 256, 0, stream>>>(xbuf, Wt1, b1, hbuf, N_NODES);
    k_gat_agg<<<(N_NODES + 3) / 4, 256, 0, stream>>>(hbuf, off, esrc, attl1, attr1,
                                                     xbuf, N_NODES, 0.01f);

    // post_mp (combined) + node output (fp32 + fp16 copy)
    k_lin64<<<LIN_NB, 256, 0, stream>>>(xbuf, Wct, bc, xo, yh, N_NODES);

    // edge scores
    k_edge_score<<<(N_EDGES * 8 + 255) / 256, 256, 0, stream>>>(yh, src, dst, out, N_EDGES);
}

// Round 9
// 232.562 us; speedup vs baseline: 1.5231x; 1.0332x over previous
//
#include <hip/hip_runtime.h>
#include <hip/hip_bf16.h>
#include <hip/hip_fp16.h>
#include <math.h>

#define N_NODES 50000
#define N_EDGES 800000
#define HC      128     // HEADS*HID
#define OUTD    64
#define NBKT    ((N_NODES + 63) / 64)   // 782 buckets of 64 nodes

// fast exp2: single v_exp_f32
#if defined(__has_builtin)
#if __has_builtin(__builtin_amdgcn_exp2f)
#define EXP2(x) __builtin_amdgcn_exp2f(x)
#endif
#endif
#ifndef EXP2
#define EXP2(x) __expf((x) * 0.69314718055994531f)
#endif

// ---------------- bucketed CSR build (round 8: WRITE_SIZE 51.6->~10MB) ------

__global__ __launch_bounds__(1024) void k_hist(const int* __restrict__ dst,
                                               int* __restrict__ bcnt, int e_cnt) {
    __shared__ int lh[NBKT];
    for (int i = threadIdx.x; i < NBKT; i += 1024) lh[i] = 0;
    __syncthreads();
    int base = blockIdx.x * 8192;
    for (int i = threadIdx.x; i < 8192; i += 1024) {
        int e = base + i;
        if (e < e_cnt) atomicAdd(&lh[dst[e] >> 6], 1);
    }
    __syncthreads();
    for (int i = threadIdx.x; i < NBKT; i += 1024) {
        int c = lh[i];
        if (c) atomicAdd(&bcnt[i], c);
    }
}

__global__ __launch_bounds__(1024) void k_bscan(const int* __restrict__ bcnt,
                                                int* __restrict__ bbase,
                                                int* __restrict__ bcur) {
    __shared__ int wsum[16];
    __shared__ int wexc[16];
    int t = threadIdx.x, lane = t & 63, wid = t >> 6;
    int v = (t < NBKT) ? bcnt[t] : 0;
    int incl = v;
    #pragma unroll
    for (int s = 1; s < 64; s <<= 1) {
        int u = __shfl_up(incl, s, 64);
        if (lane >= s) incl += u;
    }
    if (lane == 63) wsum[wid] = incl;
    __syncthreads();
    if (wid == 0 && lane < 16) {
        int w = wsum[lane];
        int wi = w;
        #pragma unroll
        for (int s = 1; s < 16; s <<= 1) {
            int u = __shfl_up(wi, s, 64);
            if (lane >= s) wi += u;
        }
        wexc[lane] = wi - w;
    }
    __syncthreads();
    int ex = wexc[wid] + incl - v;
    if (t < NBKT) { bbase[t] = ex; bcur[t] = ex; }
    if (t == NBKT - 1) bbase[NBKT] = ex + v;   // == e_cnt
}

__global__ __launch_bounds__(1024) void k_bscatter(const int* __restrict__ src,
                                                   const int* __restrict__ dst,
                                                   int* __restrict__ bcur,
                                                   uint2* __restrict__ ebuf, int e_cnt) {
    __shared__ int lcnt[NBKT];
    __shared__ int lbase[NBKT];
    for (int i = threadIdx.x; i < NBKT; i += 1024) lcnt[i] = 0;
    __syncthreads();
    int base = blockIdx.x * 8192;
    int myS[8], myD[8], myR[8];
    #pragma unroll
    for (int j = 0; j < 8; ++j) {
        int e = base + threadIdx.x + j * 1024;          // coalesced
        if (e < e_cnt) {
            myS[j] = src[e];
            myD[j] = dst[e];
            myR[j] = atomicAdd(&lcnt[myD[j] >> 6], 1);  // LDS rank (fast)
        } else myD[j] = -1;
    }
    __syncthreads();
    for (int i = threadIdx.x; i < NBKT; i += 1024) {
        int c = lcnt[i];
        lbase[i] = c ? atomicAdd(&bcur[i], c) : 0;      // reserve range once
    }
    __syncthreads();
    #pragma unroll
    for (int j = 0; j < 8; ++j) {
        if (myD[j] >= 0) {
            int bkt = myD[j] >> 6;
            ebuf[lbase[bkt] + myR[j]] =
                make_uint2((unsigned)myS[j], (unsigned)myD[j]);
        }
    }
}

__global__ __launch_bounds__(256) void k_bfinal(const uint2* __restrict__ ebuf,
                                                const int* __restrict__ bbase,
                                                int* __restrict__ off,
                                                int* __restrict__ esrc, int n) {
    __shared__ int ncnt[64];
    __shared__ int ncur[64];
    int b = blockIdx.x;
    int t = threadIdx.x;
    int ebeg = bbase[b], eend = bbase[b + 1];
    if (t < 64) ncnt[t] = 0;
    __syncthreads();
    for (int e = ebeg + t; e < eend; e += 256)
        atomicAdd(&ncnt[ebuf[e].y & 63], 1);
    __syncthreads();
    if (t < 64) {
        int v = ncnt[t];
        int incl = v;
        #pragma unroll
        for (int s = 1; s < 64; s <<= 1) {
            int u = __shfl_up(incl, s, 64);
            if (t >= s) incl += u;
        }
        int ex = incl - v;
        ncur[t] = ex;
        int node = b * 64 + t;
        if (node <= n) off[node] = ebeg + ex;   // covers off[n] via last bucket
    }
    __syncthreads();
    for (int e = ebeg + t; e < eend; e += 256) {
        uint2 ed = ebuf[e];
        int r = atomicAdd(&ncur[ed.y & 63], 1);
        esrc[ebeg + r] = (int)ed.x;             // contiguous 4KB region per block
    }
}

// ---------------- weight prep (fused: 2 transposes + post_mp combine) ----------------

__global__ void k_prep(const float* __restrict__ W0, const float* __restrict__ W1,
                       const float* __restrict__ pW1, const float* __restrict__ pb1,
                       const float* __restrict__ pW2, const float* __restrict__ pb2,
                       float* __restrict__ Wt0, float* __restrict__ Wt1,
                       float* __restrict__ Wct, float* __restrict__ bc) {
    int i = blockIdx.x * blockDim.x + threadIdx.x;
    if (i < HC * HC) {
        int r = i >> 7, c = i & 127;
        Wt0[c * HC + r] = W0[i];
        Wt1[c * HC + r] = W1[i];
    } else if (i < HC * HC + HC * OUTD) {
        int j = i - HC * HC;
        int k = j >> 6, o2 = j & 63;
        float s = 0.f;
        for (int m = 0; m < 64; ++m) s += pW2[o2 * 64 + m] * pW1[m * 128 + k];
        Wct[k * 64 + o2] = s;
    } else if (i < HC * HC + HC * OUTD + OUTD) {
        int o2 = i - HC * HC - HC * OUTD;
        float s = pb2[o2];
        for (int m = 0; m < 64; ++m) s += pW2[o2 * 64 + m] * pb1[m];
        bc[o2] = s;
    }
}

// ---------------- linear: h = x @ Wt + b, K=128, OC=128, out fp16 ----------------
// NOTE: macro params must not be named x/y/z/w (preprocessor substitutes
// member-access tokens -- round 3's compile failure).

#define FMA4(acc, wv, sv)                                                      \
    acc.x = fmaf(wv.x, sv, acc.x); acc.y = fmaf(wv.y, sv, acc.y);              \
    acc.z = fmaf(wv.z, sv, acc.z); acc.w = fmaf(wv.w, sv, acc.w);

__global__ __launch_bounds__(256) void k_lin128(const float* __restrict__ x,
                                                const float* __restrict__ Wt,
                                                const float* __restrict__ bias,
                                                __half* __restrict__ h, int n) {
    __shared__ float ws[64 * 128];      // 32KB: one K-chunk of Wt (rows = k)
    __shared__ float xs[32 * 128];      // 16KB: 32 node rows
    int t = threadIdx.x;
    int node0 = blockIdx.x * 32;
    for (int i = t; i < 1024; i += 256) {
        int row = i >> 5, c = i & 31;
        int gn = node0 + row;
        ((float4*)xs)[i] = (gn < n) ? ((const float4*)x)[(size_t)gn * 32 + c]
                                    : make_float4(0.f, 0.f, 0.f, 0.f);
    }
    int c4 = t & 31;                    // output float4 index [0,32)
    int ng = (t >> 5) * 4;              // first of my 4 nodes
    float4 bb = ((const float4*)bias)[c4];
    float4 a0 = bb, a1 = bb, a2 = bb, a3 = bb;
    const float4* xr0 = (const float4*)&xs[(ng + 0) * 128];
    const float4* xr1 = (const float4*)&xs[(ng + 1) * 128];
    const float4* xr2 = (const float4*)&xs[(ng + 2) * 128];
    const float4* xr3 = (const float4*)&xs[(ng + 3) * 128];

    for (int chunk = 0; chunk < 2; ++chunk) {
        __syncthreads();
        const float4* wsrc = (const float4*)&Wt[chunk * 64 * 128];
        for (int i = t; i < 2048; i += 256)
            ((float4*)ws)[i] = wsrc[i];
        __syncthreads();
        int kb = chunk * 16;
        #pragma unroll 4
        for (int k4 = 0; k4 < 16; ++k4) {
            float4 xv0 = xr0[kb + k4];
            float4 xv1 = xr1[kb + k4];
            float4 xv2 = xr2[kb + k4];
            float4 xv3 = xr3[kb + k4];
            const float* wr = &ws[k4 * 512];
            float4 w0 = ((const float4*)&wr[0])[c4];
            float4 w1 = ((const float4*)&wr[128])[c4];
            float4 w2 = ((const float4*)&wr[256])[c4];
            float4 w3 = ((const float4*)&wr[384])[c4];
            FMA4(a0, w0, xv0.x); FMA4(a0, w1, xv0.y); FMA4(a0, w2, xv0.z); FMA4(a0, w3, xv0.w);
            FMA4(a1, w0, xv1.x); FMA4(a1, w1, xv1.y); FMA4(a1, w2, xv1.z); FMA4(a1, w3, xv1.w);
            FMA4(a2, w0, xv2.x); FMA4(a2, w1, xv2.y); FMA4(a2, w2, xv2.z); FMA4(a2, w3, xv2.w);
            FMA4(a3, w0, xv3.x); FMA4(a3, w1, xv3.y); FMA4(a3, w2, xv3.z); FMA4(a3, w3, xv3.w);
        }
    }

    union { __half2 h2[2]; uint2 u; } p;
    int gn = node0 + ng;
    if (gn + 0 < n) { p.h2[0] = __floats2half2_rn(a0.x, a0.y); p.h2[1] = __floats2half2_rn(a0.z, a0.w);
                      *(uint2*)&h[(size_t)(gn + 0) * 128 + c4 * 4] = p.u; }
    if (gn + 1 < n) { p.h2[0] = __floats2half2_rn(a1.x, a1.y); p.h2[1] = __floats2half2_rn(a1.z, a1.w);
                      *(uint2*)&h[(size_t)(gn + 1) * 128 + c4 * 4] = p.u; }
    if (gn + 2 < n) { p.h2[0] = __floats2half2_rn(a2.x, a2.y); p.h2[1] = __floats2half2_rn(a2.z, a2.w);
                      *(uint2*)&h[(size_t)(gn + 2) * 128 + c4 * 4] = p.u; }
    if (gn + 3 < n) { p.h2[0] = __floats2half2_rn(a3.x, a3.y); p.h2[1] = __floats2half2_rn(a3.z, a3.w);
                      *(uint2*)&h[(size_t)(gn + 3) * 128 + c4 * 4] = p.u; }
}

// ---------------- GAT aggregate ----------------
// One wave per dst node, two half-waves by edge parity. Max-free log2-domain
// softmax (scores O(+-5); safety fallback below).
// Round 9: direct broadcast loads of esrc replace the staged-chunk + shfl
// scheme. All 32 lanes of a half-wave load the SAME esrc[e+half] -> one L1
// transaction (64B line = 16 edges = 8 steps of L1 reuse), and the loads for
// unrolled steps issue immediately (no ds_bpermute at the head of the gather
// dependency chain). Also deletes per-chunk staging/bounds/fullp overhead.

__global__ __launch_bounds__(256) void k_gat_agg(const __half* __restrict__ h,
                                                 const int* __restrict__ off,
                                                 const int* __restrict__ esrc,
                                                 const float* __restrict__ attl,
                                                 const float* __restrict__ attr,
                                                 float* __restrict__ xout, int n,
                                                 float neg_out) {
    const float L2E = 1.4426950408889634f;
    int wid  = threadIdx.x >> 6;
    int lane = threadIdx.x & 63;
    int node = blockIdx.x * 4 + wid;
    if (node >= n) return;
    int half = lane >> 5;               // edge parity this half-wave owns
    int cq   = lane & 31;               // channel quad index
    uint32_t cq8 = (uint32_t)cq << 3;   // byte offset of my 4 fp16 channels

    const char* hb = (const char*)h;    // uniform base (SGPR) -- saddr form

    float4 alv = ((const float4*)attl)[cq];
    float4 arv = ((const float4*)attr)[cq];
    uint2 hdr = *(const uint2*)(hb + ((((uint32_t)node << 8)) | cq8));
    float2 hd01 = __half22float2(((const __half2*)&hdr)[0]);
    float2 hd23 = __half22float2(((const __half2*)&hdr)[1]);
    float al0 = alv.x * L2E, al1 = alv.y * L2E;
    float al2 = alv.z * L2E, al3 = alv.w * L2E;
    float ar0 = arv.x * hd01.x * L2E, ar1 = arv.y * hd01.y * L2E;
    float ar2 = arv.z * hd23.x * L2E, ar3 = arv.w * hd23.y * L2E;

    float z0 = 0.f, z1 = 0.f, z2 = 0.f, z3 = 0.f;
    float a0 = 0.f, a1 = 0.f, a2 = 0.f, a3 = 0.f;

    int beg = off[node], end = off[node + 1];

#define STEP(sAv)                                                              \
    {   uint32_t voff = (((uint32_t)(sAv)) << 8) | cq8;                        \
        uint2 hv = *(const uint2*)(hb + voff);                                 \
        float2 f01 = __half22float2(((const __half2*)&hv)[0]);                 \
        float2 f23 = __half22float2(((const __half2*)&hv)[1]);                 \
        float t0 = fmaf(al0, f01.x, ar0), t1 = fmaf(al1, f01.y, ar1);          \
        float t2 = fmaf(al2, f23.x, ar2), t3 = fmaf(al3, f23.y, ar3);          \
        float e0 = EXP2(fmaxf(t0, 0.2f * t0)), e1 = EXP2(fmaxf(t1, 0.2f * t1));\
        float e2 = EXP2(fmaxf(t2, 0.2f * t2)), e3 = EXP2(fmaxf(t3, 0.2f * t3));\
        z0 += e0; z1 += e1; z2 += e2; z3 += e3;                                \
        a0 = fmaf(e0, f01.x, a0); a1 = fmaf(e1, f01.y, a1);                    \
        a2 = fmaf(e2, f23.x, a2); a3 = fmaf(e3, f23.y, a3);                    \
    }

    {
        int e = beg;
        #pragma unroll 4
        for (; e + 2 <= end; e += 2) {
            int sA = esrc[e + half];    // half-wave-uniform -> L1 broadcast
            STEP(sA);
        }
        if (e < end) {                  // one leftover edge (even parity)
            int sA = esrc[end - 1];
            if (half == 0) STEP(sA);
        }
    }
#undef STEP

    // validity: overflow -> z inf/NaN; total underflow -> z==0 with edges
    float zs = z0 + z1 + z2 + z3;
    bool bad = !(zs < 3.0e38f);
    if (beg < end)
        bad = bad || !((z0 > 0.f) && (z1 > 0.f) && (z2 > 0.f) && (z3 > 0.f));

    if (__any(bad)) {
        // slow safe path (~never): two-pass max-shifted softmax; every lane
        // walks ALL edges, so both halves hold identical full sums (no merge).
        float m0 = -1e30f, m1 = -1e30f, m2 = -1e30f, m3 = -1e30f;
        for (int e = beg; e < end; ++e) {
            int sA = esrc[e];
            uint2 hv = *(const uint2*)(hb + (((uint32_t)sA << 8) | cq8));
            float2 f01 = __half22float2(((const __half2*)&hv)[0]);
            float2 f23 = __half22float2(((const __half2*)&hv)[1]);
            float t0 = fmaf(al0, f01.x, ar0), t1 = fmaf(al1, f01.y, ar1);
            float t2 = fmaf(al2, f23.x, ar2), t3 = fmaf(al3, f23.y, ar3);
            m0 = fmaxf(m0, fmaxf(t0, 0.2f * t0));
            m1 = fmaxf(m1, fmaxf(t1, 0.2f * t1));
            m2 = fmaxf(m2, fmaxf(t2, 0.2f * t2));
            m3 = fmaxf(m3, fmaxf(t3, 0.2f * t3));
        }
        z0 = z1 = z2 = z3 = 0.f;
        a0 = a1 = a2 = a3 = 0.f;
        for (int e = beg; e < end; ++e) {
            int sA = esrc[e];
            uint2 hv = *(const uint2*)(hb + (((uint32_t)sA << 8) | cq8));
            float2 f01 = __half22float2(((const __half2*)&hv)[0]);
            float2 f23 = __half22float2(((const __half2*)&hv)[1]);
            float t0 = fmaf(al0, f01.x, ar0), t1 = fmaf(al1, f01.y, ar1);
            float t2 = fmaf(al2, f23.x, ar2), t3 = fmaf(al3, f23.y, ar3);
            float e0 = EXP2(fmaxf(t0, 0.2f * t0) - m0);
            float e1 = EXP2(fmaxf(t1, 0.2f * t1) - m1);
            float e2 = EXP2(fmaxf(t2, 0.2f * t2) - m2);
            float e3 = EXP2(fmaxf(t3, 0.2f * t3) - m3);
            z0 += e0; z1 += e1; z2 += e2; z3 += e3;
            a0 = fmaf(e0, f01.x, a0); a1 = fmaf(e1, f01.y, a1);
            a2 = fmaf(e2, f23.x, a2); a3 = fmaf(e3, f23.y, a3);
        }
    } else {
        // merge parity halves: plain adds (shared implicit reference)
        z0 += __shfl_xor(z0, 32, 64); z1 += __shfl_xor(z1, 32, 64);
        z2 += __shfl_xor(z2, 32, 64); z3 += __shfl_xor(z3, 32, 64);
        a0 += __shfl_xor(a0, 32, 64); a1 += __shfl_xor(a1, 32, 64);
        a2 += __shfl_xor(a2, 32, 64); a3 += __shfl_xor(a3, 32, 64);
    }

    if (half == 0) {
        float o0 = (z0 > 0.f) ? a0 / z0 : 0.f;
        float o1 = (z1 > 0.f) ? a1 / z1 : 0.f;
        float o2 = (z2 > 0.f) ? a2 / z2 : 0.f;
        float o3 = (z3 > 0.f) ? a3 / z3 : 0.f;
        o0 = fmaxf(o0, neg_out * o0);
        o1 = fmaxf(o1, neg_out * o1);
        o2 = fmaxf(o2, neg_out * o2);
        o3 = fmaxf(o3, neg_out * o3);
        *(float4*)&xout[(size_t)node * 128 + cq * 4] = make_float4(o0, o1, o2, o3);
    }
}

// ---------------- final linear K=128 -> 64: LDS-staged Wct ----------------

__global__ __launch_bounds__(256) void k_lin64(const float* __restrict__ x,
                                               const float* __restrict__ Wct,
                                               const float* __restrict__ bc,
                                               float* __restrict__ y,
                                               __half* __restrict__ yh, int n) {
    __shared__ float ws[128 * 64];      // 32KB, row k: 64 outputs
    __shared__ float xs[32 * 128];      // 16KB
    int t = threadIdx.x;
    int node0 = blockIdx.x * 32;
    for (int i = t; i < 2048; i += 256)
        ((float4*)ws)[i] = ((const float4*)Wct)[i];
    for (int i = t; i < 1024; i += 256) {
        int row = i >> 5, c = i & 31;
        int gn = node0 + row;
        ((float4*)xs)[i] = (gn < n) ? ((const float4*)x)[(size_t)gn * 32 + c]
                                    : make_float4(0.f, 0.f, 0.f, 0.f);
    }
    __syncthreads();
    int l = t & 15;                     // output float4 index [0,16)
    int ng = (t >> 4) * 2;              // first of my 2 nodes
    float4 bb = ((const float4*)bc)[l];
    float4 a0 = bb, a1 = bb;
    const float4* xr0 = (const float4*)&xs[(ng + 0) * 128];
    const float4* xr1 = (const float4*)&xs[(ng + 1) * 128];
    #pragma unroll 4
    for (int k4 = 0; k4 < 32; ++k4) {
        float4 xv0 = xr0[k4];
        float4 xv1 = xr1[k4];
        const float* wr = &ws[k4 * 256];
        float4 w0 = ((const float4*)&wr[0])[l];
        float4 w1 = ((const float4*)&wr[64])[l];
        float4 w2 = ((const float4*)&wr[128])[l];
        float4 w3 = ((const float4*)&wr[192])[l];
        FMA4(a0, w0, xv0.x); FMA4(a0, w1, xv0.y); FMA4(a0, w2, xv0.z); FMA4(a0, w3, xv0.w);
        FMA4(a1, w0, xv1.x); FMA4(a1, w1, xv1.y); FMA4(a1, w2, xv1.z); FMA4(a1, w3, xv1.w);
    }
    union { __half2 h2[2]; uint2 u; } p;
    int gn = node0 + ng;
    if (gn + 0 < n) {
        ((float4*)&y[(size_t)(gn + 0) * 64])[l] = a0;
        p.h2[0] = __floats2half2_rn(a0.x, a0.y); p.h2[1] = __floats2half2_rn(a0.z, a0.w);
        *(uint2*)&yh[(size_t)(gn + 0) * 64 + l * 4] = p.u;
    }
    if (gn + 1 < n) {
        ((float4*)&y[(size_t)(gn + 1) * 64])[l] = a1;
        p.h2[0] = __floats2half2_rn(a1.x, a1.y); p.h2[1] = __floats2half2_rn(a1.z, a1.w);
        *(uint2*)&yh[(size_t)(gn + 1) * 64 + l * 4] = p.u;
    }
}

// ---------------- edge scores: sigmoid(dot(x[src], x[dst])), fp16 gather, 8 lanes/edge ----------------

__global__ __launch_bounds__(256) void k_edge_score(const __half* __restrict__ xh,
                                                    const int* __restrict__ src,
                                                    const int* __restrict__ dst,
                                                    float* __restrict__ out, int e_cnt) {
    int t = blockIdx.x * 256 + threadIdx.x;
    int e = t >> 3;
    int l = t & 7;
    if (e >= e_cnt) return;
    int u = src[e], v = dst[e];
    uint4 ua = ((const uint4*)&xh[(size_t)u * 64])[l];
    uint4 vb = ((const uint4*)&xh[(size_t)v * 64])[l];
    const __half2* pa = (const __half2*)&ua;
    const __half2* pb = (const __half2*)&vb;
    float d = 0.f;
    #pragma unroll
    for (int j = 0; j < 4; ++j) {
        float2 fa = __half22float2(pa[j]);
        float2 fb = __half22float2(pb[j]);
        d = fmaf(fa.x, fb.x, d);
        d = fmaf(fa.y, fb.y, d);
    }
    d += __shfl_xor(d, 1);
    d += __shfl_xor(d, 2);
    d += __shfl_xor(d, 4);
    if (l == 0) out[e] = 1.f / (1.f + __expf(-d));
}

// ---------------- launch ----------------

extern "C" void kernel_launch(void* const* d_in, const int* in_sizes, int n_in,
                              void* d_out, int out_size, void* d_ws, size_t ws_size,
                              hipStream_t stream) {
    const float* emb   = (const float*)d_in[0];
    const int*   ei    = (const int*)d_in[1];
    const float* W0    = (const float*)d_in[2];
    const float* b0    = (const float*)d_in[3];
    const float* attl0 = (const float*)d_in[4];
    const float* attr0 = (const float*)d_in[5];
    const float* W1    = (const float*)d_in[6];
    const float* b1    = (const float*)d_in[7];
    const float* attl1 = (const float*)d_in[8];
    const float* attr1 = (const float*)d_in[9];
    const float* pW1   = (const float*)d_in[10];
    const float* pb1   = (const float*)d_in[11];
    const float* pW2   = (const float*)d_in[12];
    const float* pb2   = (const float*)d_in[13];

    const int* src = ei;
    const int* dst = ei + N_EDGES;

    float* out = (float*)d_out;          // [E]
    float* xo  = out + N_EDGES;          // [N,64] fp32 node output

    char* ws = (char*)d_ws;
    size_t o = 0;
    auto alloc = [&](size_t bytes) {
        char* p = ws + o;
        o = (o + bytes + 255) & ~(size_t)255;
        return p;
    };
    int*    off   = (int*)alloc((size_t)(N_NODES + 1) * 4);
    int*    esrc  = (int*)alloc((size_t)N_EDGES * 4);
    int*    bcnt  = (int*)alloc((size_t)(NBKT + 1) * 4);
    int*    bbase = (int*)alloc((size_t)(NBKT + 1) * 4);
    int*    bcur  = (int*)alloc((size_t)(NBKT + 1) * 4);
    uint2*  ebuf  = (uint2*)alloc((size_t)N_EDGES * 8);
    __half* hbuf  = (__half*)alloc((size_t)N_NODES * HC * 2);
    float*  xbuf  = (float*)alloc((size_t)N_NODES * HC * 4);
    __half* yh    = (__half*)alloc((size_t)N_NODES * OUTD * 2);
    float*  Wt0   = (float*)alloc((size_t)HC * HC * 4);
    float*  Wt1   = (float*)alloc((size_t)HC * HC * 4);
    float*  Wct   = (float*)alloc((size_t)HC * OUTD * 4);
    float*  bc    = (float*)alloc((size_t)OUTD * 4);
    (void)ws_size; (void)in_sizes; (void)n_in; (void)out_size;

    const int LIN_NB = (N_NODES + 31) / 32;        // 1563
    const int EB_NB  = (N_EDGES + 8191) / 8192;    // 98
    const int PREP_N = HC * HC + HC * OUTD + OUTD;

    // weight prep (independent of everything else)
    k_prep<<<(PREP_N + 255) / 256, 256, 0, stream>>>(W0, W1, pW1, pb1, pW2, pb2,
                                                     Wt0, Wt1, Wct, bc);

    // bucketed CSR build
    hipMemsetAsync(bcnt, 0, (size_t)(NBKT + 1) * 4, stream);
    k_hist    <<<EB_NB, 1024, 0, stream>>>(dst, bcnt, N_EDGES);
    k_bscan   <<<1, 1024, 0, stream>>>(bcnt, bbase, bcur);
    k_bscatter<<<EB_NB, 1024, 0, stream>>>(src, dst, bcur, ebuf, N_EDGES);
    k_bfinal  <<<NBKT, 256, 0, stream>>>(ebuf, bbase, off, esrc, N_NODES);

    // GAT layer 0
    k_lin128<<<LIN_NB, 256, 0, stream>>>(emb, Wt0, b0, hbuf, N_NODES);
    k_gat_agg<<<(N_NODES + 3) / 4, 256, 0, stream>>>(hbuf, off, esrc, attl0, attr0,
                                                     xbuf, N_NODES, 0.01f);
    // GAT layer 1
    k_lin128<<<LIN_NB, 256, 0, stream>>>(xbuf, Wt1, b1, hbuf, N_NODES);
    k_gat_agg<<<(N_NODES + 3) / 4, 256, 0, stream>>>(hbuf, off, esrc, attl1, attr1,
                                                     xbuf, N_NODES, 0.01f);

    // post_mp (combined) + node output (fp32 + fp16 copy)
    k_lin64<<<LIN_NB, 256, 0, stream>>>(xbuf, Wct, bc, xo, yh, N_NODES);

    // edge scores
    k_edge_score<<<(N_EDGES * 8 + 255) / 256, 256, 0, stream>>>(yh, src, dst, out, N_EDGES);
}

// Round 10
// 231.371 us; speedup vs baseline: 1.5309x; 1.0051x over previous
//
#include <hip/hip_runtime.h>
#include <hip/hip_bf16.h>
#include <hip/hip_fp16.h>
#include <math.h>

#define N_NODES 50000
#define N_EDGES 800000
#define HC      128     // HEADS*HID
#define OUTD    64
#define NBKT    ((N_NODES + 63) / 64)   // 782 buckets of 64 nodes

// fast exp2: single v_exp_f32
#if defined(__has_builtin)
#if __has_builtin(__builtin_amdgcn_exp2f)
#define EXP2(x) __builtin_amdgcn_exp2f(x)
#endif
#endif
#ifndef EXP2
#define EXP2(x) __expf((x) * 0.69314718055994531f)
#endif

// ---------------- bucketed CSR build (round 8: WRITE_SIZE 51.6->~10MB) ------

__global__ __launch_bounds__(1024) void k_hist(const int* __restrict__ dst,
                                               int* __restrict__ bcnt, int e_cnt) {
    __shared__ int lh[NBKT];
    for (int i = threadIdx.x; i < NBKT; i += 1024) lh[i] = 0;
    __syncthreads();
    int base = blockIdx.x * 8192;
    for (int i = threadIdx.x; i < 8192; i += 1024) {
        int e = base + i;
        if (e < e_cnt) atomicAdd(&lh[dst[e] >> 6], 1);
    }
    __syncthreads();
    for (int i = threadIdx.x; i < NBKT; i += 1024) {
        int c = lh[i];
        if (c) atomicAdd(&bcnt[i], c);
    }
}

__global__ __launch_bounds__(1024) void k_bscan(const int* __restrict__ bcnt,
                                                int* __restrict__ bbase,
                                                int* __restrict__ bcur) {
    __shared__ int wsum[16];
    __shared__ int wexc[16];
    int t = threadIdx.x, lane = t & 63, wid = t >> 6;
    int v = (t < NBKT) ? bcnt[t] : 0;
    int incl = v;
    #pragma unroll
    for (int s = 1; s < 64; s <<= 1) {
        int u = __shfl_up(incl, s, 64);
        if (lane >= s) incl += u;
    }
    if (lane == 63) wsum[wid] = incl;
    __syncthreads();
    if (wid == 0 && lane < 16) {
        int w = wsum[lane];
        int wi = w;
        #pragma unroll
        for (int s = 1; s < 16; s <<= 1) {
            int u = __shfl_up(wi, s, 64);
            if (lane >= s) wi += u;
        }
        wexc[lane] = wi - w;
    }
    __syncthreads();
    int ex = wexc[wid] + incl - v;
    if (t < NBKT) { bbase[t] = ex; bcur[t] = ex; }
    if (t == NBKT - 1) bbase[NBKT] = ex + v;   // == e_cnt
}

__global__ __launch_bounds__(1024) void k_bscatter(const int* __restrict__ src,
                                                   const int* __restrict__ dst,
                                                   int* __restrict__ bcur,
                                                   uint2* __restrict__ ebuf, int e_cnt) {
    __shared__ int lcnt[NBKT];
    __shared__ int lbase[NBKT];
    for (int i = threadIdx.x; i < NBKT; i += 1024) lcnt[i] = 0;
    __syncthreads();
    int base = blockIdx.x * 8192;
    int myS[8], myD[8], myR[8];
    #pragma unroll
    for (int j = 0; j < 8; ++j) {
        int e = base + threadIdx.x + j * 1024;          // coalesced
        if (e < e_cnt) {
            myS[j] = src[e];
            myD[j] = dst[e];
            myR[j] = atomicAdd(&lcnt[myD[j] >> 6], 1);  // LDS rank (fast)
        } else myD[j] = -1;
    }
    __syncthreads();
    for (int i = threadIdx.x; i < NBKT; i += 1024) {
        int c = lcnt[i];
        lbase[i] = c ? atomicAdd(&bcur[i], c) : 0;      // reserve range once
    }
    __syncthreads();
    #pragma unroll
    for (int j = 0; j < 8; ++j) {
        if (myD[j] >= 0) {
            int bkt = myD[j] >> 6;
            ebuf[lbase[bkt] + myR[j]] =
                make_uint2((unsigned)myS[j], (unsigned)myD[j]);
        }
    }
}

__global__ __launch_bounds__(256) void k_bfinal(const uint2* __restrict__ ebuf,
                                                const int* __restrict__ bbase,
                                                int* __restrict__ off,
                                                int* __restrict__ esrc, int n) {
    __shared__ int ncnt[64];
    __shared__ int ncur[64];
    int b = blockIdx.x;
    int t = threadIdx.x;
    int ebeg = bbase[b], eend = bbase[b + 1];
    if (t < 64) ncnt[t] = 0;
    __syncthreads();
    for (int e = ebeg + t; e < eend; e += 256)
        atomicAdd(&ncnt[ebuf[e].y & 63], 1);
    __syncthreads();
    if (t < 64) {
        int v = ncnt[t];
        int incl = v;
        #pragma unroll
        for (int s = 1; s < 64; s <<= 1) {
            int u = __shfl_up(incl, s, 64);
            if (t >= s) incl += u;
        }
        int ex = incl - v;
        ncur[t] = ex;
        int node = b * 64 + t;
        if (node <= n) off[node] = ebeg + ex;   // covers off[n] via last bucket
    }
    __syncthreads();
    for (int e = ebeg + t; e < eend; e += 256) {
        uint2 ed = ebuf[e];
        int r = atomicAdd(&ncur[ed.y & 63], 1);
        esrc[ebeg + r] = (int)ed.x;             // contiguous 4KB region per block
    }
}

// ---------------- weight prep (fused: 2 transposes + post_mp combine) ----------------

__global__ void k_prep(const float* __restrict__ W0, const float* __restrict__ W1,
                       const float* __restrict__ pW1, const float* __restrict__ pb1,
                       const float* __restrict__ pW2, const float* __restrict__ pb2,
                       float* __restrict__ Wt0, float* __restrict__ Wt1,
                       float* __restrict__ Wct, float* __restrict__ bc) {
    int i = blockIdx.x * blockDim.x + threadIdx.x;
    if (i < HC * HC) {
        int r = i >> 7, c = i & 127;
        Wt0[c * HC + r] = W0[i];
        Wt1[c * HC + r] = W1[i];
    } else if (i < HC * HC + HC * OUTD) {
        int j = i - HC * HC;
        int k = j >> 6, o2 = j & 63;
        float s = 0.f;
        for (int m = 0; m < 64; ++m) s += pW2[o2 * 64 + m] * pW1[m * 128 + k];
        Wct[k * 64 + o2] = s;
    } else if (i < HC * HC + HC * OUTD + OUTD) {
        int o2 = i - HC * HC - HC * OUTD;
        float s = pb2[o2];
        for (int m = 0; m < 64; ++m) s += pW2[o2 * 64 + m] * pb1[m];
        bc[o2] = s;
    }
}

// ---------------- linear: h = x @ Wt + b, K=128, OC=128, out fp16 ----------------
// Round 10: round-9 pmc showed the 48KB-LDS version at Occupancy 16%,
// VALUBusy 26% -- latency-bound at ~1-3 blocks/CU. Shrink to 24KB/block:
// 16 nodes (xs 8KB) + 16KB weight chunks (4 chunks). 6 blocks/CU by LDS,
// per-thread 2 nodes x 4 ch (VGPR ~50). Same math, bit-identical.
// NOTE: macro params must not be named x/y/z/w (preprocessor substitutes
// member-access tokens -- round 3's compile failure).

#define FMA4(acc, wv, sv)                                                      \
    acc.x = fmaf(wv.x, sv, acc.x); acc.y = fmaf(wv.y, sv, acc.y);              \
    acc.z = fmaf(wv.z, sv, acc.z); acc.w = fmaf(wv.w, sv, acc.w);

__global__ __launch_bounds__(256) void k_lin128(const float* __restrict__ x,
                                                const float* __restrict__ Wt,
                                                const float* __restrict__ bias,
                                                __half* __restrict__ h, int n) {
    __shared__ float ws[32 * 128];      // 16KB: one K-chunk of Wt (32 k-rows)
    __shared__ float xs[16 * 128];      // 8KB: 16 node rows
    int t = threadIdx.x;
    int node0 = blockIdx.x * 16;
    for (int i = t; i < 512; i += 256) {
        int row = i >> 5, c = i & 31;
        int gn = node0 + row;
        ((float4*)xs)[i] = (gn < n) ? ((const float4*)x)[(size_t)gn * 32 + c]
                                    : make_float4(0.f, 0.f, 0.f, 0.f);
    }
    int c4 = t & 31;                    // output float4 index [0,32)
    int ng = (t >> 5) * 2;              // first of my 2 nodes
    float4 bb = ((const float4*)bias)[c4];
    float4 a0 = bb, a1 = bb;
    const float4* xr0 = (const float4*)&xs[(ng + 0) * 128];
    const float4* xr1 = (const float4*)&xs[(ng + 1) * 128];

    for (int chunk = 0; chunk < 4; ++chunk) {
        __syncthreads();                // x ready (c=0) / ws no longer read
        const float4* wsrc = (const float4*)&Wt[chunk * 32 * 128];
        for (int i = t; i < 1024; i += 256)
            ((float4*)ws)[i] = wsrc[i];
        __syncthreads();
        int kb = chunk * 8;
        #pragma unroll
        for (int k4 = 0; k4 < 8; ++k4) {
            float4 xv0 = xr0[kb + k4];
            float4 xv1 = xr1[kb + k4];
            const float* wr = &ws[k4 * 512];
            float4 w0 = ((const float4*)&wr[0])[c4];
            float4 w1 = ((const float4*)&wr[128])[c4];
            float4 w2 = ((const float4*)&wr[256])[c4];
            float4 w3 = ((const float4*)&wr[384])[c4];
            FMA4(a0, w0, xv0.x); FMA4(a0, w1, xv0.y); FMA4(a0, w2, xv0.z); FMA4(a0, w3, xv0.w);
            FMA4(a1, w0, xv1.x); FMA4(a1, w1, xv1.y); FMA4(a1, w2, xv1.z); FMA4(a1, w3, xv1.w);
        }
    }

    union { __half2 h2[2]; uint2 u; } p;
    int gn = node0 + ng;
    if (gn + 0 < n) { p.h2[0] = __floats2half2_rn(a0.x, a0.y); p.h2[1] = __floats2half2_rn(a0.z, a0.w);
                      *(uint2*)&h[(size_t)(gn + 0) * 128 + c4 * 4] = p.u; }
    if (gn + 1 < n) { p.h2[0] = __floats2half2_rn(a1.x, a1.y); p.h2[1] = __floats2half2_rn(a1.z, a1.w);
                      *(uint2*)&h[(size_t)(gn + 1) * 128 + c4 * 4] = p.u; }
}

// ---------------- GAT aggregate (unchanged from round 9) ----------------

__global__ __launch_bounds__(256) void k_gat_agg(const __half* __restrict__ h,
                                                 const int* __restrict__ off,
                                                 const int* __restrict__ esrc,
                                                 const float* __restrict__ attl,
                                                 const float* __restrict__ attr,
                                                 float* __restrict__ xout, int n,
                                                 float neg_out) {
    const float L2E = 1.4426950408889634f;
    int wid  = threadIdx.x >> 6;
    int lane = threadIdx.x & 63;
    int node = blockIdx.x * 4 + wid;
    if (node >= n) return;
    int half = lane >> 5;               // edge parity this half-wave owns
    int cq   = lane & 31;               // channel quad index
    uint32_t cq8 = (uint32_t)cq << 3;   // byte offset of my 4 fp16 channels

    const char* hb = (const char*)h;    // uniform base (SGPR) -- saddr form

    float4 alv = ((const float4*)attl)[cq];
    float4 arv = ((const float4*)attr)[cq];
    uint2 hdr = *(const uint2*)(hb + ((((uint32_t)node << 8)) | cq8));
    float2 hd01 = __half22float2(((const __half2*)&hdr)[0]);
    float2 hd23 = __half22float2(((const __half2*)&hdr)[1]);
    float al0 = alv.x * L2E, al1 = alv.y * L2E;
    float al2 = alv.z * L2E, al3 = alv.w * L2E;
    float ar0 = arv.x * hd01.x * L2E, ar1 = arv.y * hd01.y * L2E;
    float ar2 = arv.z * hd23.x * L2E, ar3 = arv.w * hd23.y * L2E;

    float z0 = 0.f, z1 = 0.f, z2 = 0.f, z3 = 0.f;
    float a0 = 0.f, a1 = 0.f, a2 = 0.f, a3 = 0.f;

    int beg = off[node], end = off[node + 1];

#define STEP(sAv)                                                              \
    {   uint32_t voff = (((uint32_t)(sAv)) << 8) | cq8;                        \
        uint2 hv = *(const uint2*)(hb + voff);                                 \
        float2 f01 = __half22float2(((const __half2*)&hv)[0]);                 \
        float2 f23 = __half22float2(((const __half2*)&hv)[1]);                 \
        float t0 = fmaf(al0, f01.x, ar0), t1 = fmaf(al1, f01.y, ar1);          \
        float t2 = fmaf(al2, f23.x, ar2), t3 = fmaf(al3, f23.y, ar3);          \
        float e0 = EXP2(fmaxf(t0, 0.2f * t0)), e1 = EXP2(fmaxf(t1, 0.2f * t1));\
        float e2 = EXP2(fmaxf(t2, 0.2f * t2)), e3 = EXP2(fmaxf(t3, 0.2f * t3));\
        z0 += e0; z1 += e1; z2 += e2; z3 += e3;                                \
        a0 = fmaf(e0, f01.x, a0); a1 = fmaf(e1, f01.y, a1);                    \
        a2 = fmaf(e2, f23.x, a2); a3 = fmaf(e3, f23.y, a3);                    \
    }

    {
        int e = beg;
        #pragma unroll 4
        for (; e + 2 <= end; e += 2) {
            int sA = esrc[e + half];    // half-wave-uniform -> L1 broadcast
            STEP(sA);
        }
        if (e < end) {                  // one leftover edge (even parity)
            int sA = esrc[end - 1];
            if (half == 0) STEP(sA);
        }
    }
#undef STEP

    // validity: overflow -> z inf/NaN; total underflow -> z==0 with edges
    float zs = z0 + z1 + z2 + z3;
    bool bad = !(zs < 3.0e38f);
    if (beg < end)
        bad = bad || !((z0 > 0.f) && (z1 > 0.f) && (z2 > 0.f) && (z3 > 0.f));

    if (__any(bad)) {
        // slow safe path (~never): two-pass max-shifted softmax; every lane
        // walks ALL edges, so both halves hold identical full sums (no merge).
        float m0 = -1e30f, m1 = -1e30f, m2 = -1e30f, m3 = -1e30f;
        for (int e = beg; e < end; ++e) {
            int sA = esrc[e];
            uint2 hv = *(const uint2*)(hb + (((uint32_t)sA << 8) | cq8));
            float2 f01 = __half22float2(((const __half2*)&hv)[0]);
            float2 f23 = __half22float2(((const __half2*)&hv)[1]);
            float t0 = fmaf(al0, f01.x, ar0), t1 = fmaf(al1, f01.y, ar1);
            float t2 = fmaf(al2, f23.x, ar2), t3 = fmaf(al3, f23.y, ar3);
            m0 = fmaxf(m0, fmaxf(t0, 0.2f * t0));
            m1 = fmaxf(m1, fmaxf(t1, 0.2f * t1));
            m2 = fmaxf(m2, fmaxf(t2, 0.2f * t2));
            m3 = fmaxf(m3, fmaxf(t3, 0.2f * t3));
        }
        z0 = z1 = z2 = z3 = 0.f;
        a0 = a1 = a2 = a3 = 0.f;
        for (int e = beg; e < end; ++e) {
            int sA = esrc[e];
            uint2 hv = *(const uint2*)(hb + (((uint32_t)sA << 8) | cq8));
            float2 f01 = __half22float2(((const __half2*)&hv)[0]);
            float2 f23 = __half22float2(((const __half2*)&hv)[1]);
            float t0 = fmaf(al0, f01.x, ar0), t1 = fmaf(al1, f01.y, ar1);
            float t2 = fmaf(al2, f23.x, ar2), t3 = fmaf(al3, f23.y, ar3);
            float e0 = EXP2(fmaxf(t0, 0.2f * t0) - m0);
            float e1 = EXP2(fmaxf(t1, 0.2f * t1) - m1);
            float e2 = EXP2(fmaxf(t2, 0.2f * t2) - m2);
            float e3 = EXP2(fmaxf(t3, 0.2f * t3) - m3);
            z0 += e0; z1 += e1; z2 += e2; z3 += e3;
            a0 = fmaf(e0, f01.x, a0); a1 = fmaf(e1, f01.y, a1);
            a2 = fmaf(e2, f23.x, a2); a3 = fmaf(e3, f23.y, a3);
        }
    } else {
        // merge parity halves: plain adds (shared implicit reference)
        z0 += __shfl_xor(z0, 32, 64); z1 += __shfl_xor(z1, 32, 64);
        z2 += __shfl_xor(z2, 32, 64); z3 += __shfl_xor(z3, 32, 64);
        a0 += __shfl_xor(a0, 32, 64); a1 += __shfl_xor(a1, 32, 64);
        a2 += __shfl_xor(a2, 32, 64); a3 += __shfl_xor(a3, 32, 64);
    }

    if (half == 0) {
        float o0 = (z0 > 0.f) ? a0 / z0 : 0.f;
        float o1 = (z1 > 0.f) ? a1 / z1 : 0.f;
        float o2 = (z2 > 0.f) ? a2 / z2 : 0.f;
        float o3 = (z3 > 0.f) ? a3 / z3 : 0.f;
        o0 = fmaxf(o0, neg_out * o0);
        o1 = fmaxf(o1, neg_out * o1);
        o2 = fmaxf(o2, neg_out * o2);
        o3 = fmaxf(o3, neg_out * o3);
        *(float4*)&xout[(size_t)node * 128 + cq * 4] = make_float4(o0, o1, o2, o3);
    }
}

// ---------------- final linear K=128 -> 64: 24KB LDS (16 nodes, 2 chunks) ----

__global__ __launch_bounds__(256) void k_lin64(const float* __restrict__ x,
                                               const float* __restrict__ Wct,
                                               const float* __restrict__ bc,
                                               float* __restrict__ y,
                                               __half* __restrict__ yh, int n) {
    __shared__ float ws[64 * 64];       // 16KB: one K-chunk of Wct (64 k-rows)
    __shared__ float xs[16 * 128];      // 8KB
    int t = threadIdx.x;
    int node0 = blockIdx.x * 16;
    for (int i = t; i < 512; i += 256) {
        int row = i >> 5, c = i & 31;
        int gn = node0 + row;
        ((float4*)xs)[i] = (gn < n) ? ((const float4*)x)[(size_t)gn * 32 + c]
                                    : make_float4(0.f, 0.f, 0.f, 0.f);
    }
    int l = t & 15;                     // output float4 index [0,16)
    int g = t >> 4;                     // my node [0,16)
    float4 acc = ((const float4*)bc)[l];
    const float4* xr = (const float4*)&xs[g * 128];

    for (int chunk = 0; chunk < 2; ++chunk) {
        __syncthreads();
        const float4* wsrc = (const float4*)&Wct[chunk * 64 * 64];
        for (int i = t; i < 1024; i += 256)
            ((float4*)ws)[i] = wsrc[i];
        __syncthreads();
        int kb = chunk * 16;
        #pragma unroll 4
        for (int k4 = 0; k4 < 16; ++k4) {
            float4 xv = xr[kb + k4];
            const float* wr = &ws[k4 * 256];
            float4 w0 = ((const float4*)&wr[0])[l];
            float4 w1 = ((const float4*)&wr[64])[l];
            float4 w2 = ((const float4*)&wr[128])[l];
            float4 w3 = ((const float4*)&wr[192])[l];
            FMA4(acc, w0, xv.x); FMA4(acc, w1, xv.y);
            FMA4(acc, w2, xv.z); FMA4(acc, w3, xv.w);
        }
    }

    int gn = node0 + g;
    if (gn < n) {
        ((float4*)&y[(size_t)gn * 64])[l] = acc;
        union { __half2 h2[2]; uint2 u; } p;
        p.h2[0] = __floats2half2_rn(acc.x, acc.y);
        p.h2[1] = __floats2half2_rn(acc.z, acc.w);
        *(uint2*)&yh[(size_t)gn * 64 + l * 4] = p.u;
    }
}

// ---------------- edge scores: sigmoid(dot(x[src], x[dst])), fp16 gather, 8 lanes/edge ----------------

__global__ __launch_bounds__(256) void k_edge_score(const __half* __restrict__ xh,
                                                    const int* __restrict__ src,
                                                    const int* __restrict__ dst,
                                                    float* __restrict__ out, int e_cnt) {
    int t = blockIdx.x * 256 + threadIdx.x;
    int e = t >> 3;
    int l = t & 7;
    if (e >= e_cnt) return;
    int u = src[e], v = dst[e];
    uint4 ua = ((const uint4*)&xh[(size_t)u * 64])[l];
    uint4 vb = ((const uint4*)&xh[(size_t)v * 64])[l];
    const __half2* pa = (const __half2*)&ua;
    const __half2* pb = (const __half2*)&vb;
    float d = 0.f;
    #pragma unroll
    for (int j = 0; j < 4; ++j) {
        float2 fa = __half22float2(pa[j]);
        float2 fb = __half22float2(pb[j]);
        d = fmaf(fa.x, fb.x, d);
        d = fmaf(fa.y, fb.y, d);
    }
    d += __shfl_xor(d, 1);
    d += __shfl_xor(d, 2);
    d += __shfl_xor(d, 4);
    if (l == 0) out[e] = 1.f / (1.f + __expf(-d));
}

// ---------------- launch ----------------

extern "C" void kernel_launch(void* const* d_in, const int* in_sizes, int n_in,
                              void* d_out, int out_size, void* d_ws, size_t ws_size,
                              hipStream_t stream) {
    const float* emb   = (const float*)d_in[0];
    const int*   ei    = (const int*)d_in[1];
    const float* W0    = (const float*)d_in[2];
    const float* b0    = (const float*)d_in[3];
    const float* attl0 = (const float*)d_in[4];
    const float* attr0 = (const float*)d_in[5];
    const float* W1    = (const float*)d_in[6];
    const float* b1    = (const float*)d_in[7];
    const float* attl1 = (const float*)d_in[8];
    const float* attr1 = (const float*)d_in[9];
    const float* pW1   = (const float*)d_in[10];
    const float* pb1   = (const float*)d_in[11];
    const float* pW2   = (const float*)d_in[12];
    const float* pb2   = (const float*)d_in[13];

    const int* src = ei;
    const int* dst = ei + N_EDGES;

    float* out = (float*)d_out;          // [E]
    float* xo  = out + N_EDGES;          // [N,64] fp32 node output

    char* ws = (char*)d_ws;
    size_t o = 0;
    auto alloc = [&](size_t bytes) {
        char* p = ws + o;
        o = (o + bytes + 255) & ~(size_t)255;
        return p;
    };
    int*    off   = (int*)alloc((size_t)(N_NODES + 1) * 4);
    int*    esrc  = (int*)alloc((size_t)N_EDGES * 4);
    int*    bcnt  = (int*)alloc((size_t)(NBKT + 1) * 4);
    int*    bbase = (int*)alloc((size_t)(NBKT + 1) * 4);
    int*    bcur  = (int*)alloc((size_t)(NBKT + 1) * 4);
    uint2*  ebuf  = (uint2*)alloc((size_t)N_EDGES * 8);
    __half* hbuf  = (__half*)alloc((size_t)N_NODES * HC * 2);
    float*  xbuf  = (float*)alloc((size_t)N_NODES * HC * 4);
    __half* yh    = (__half*)alloc((size_t)N_NODES * OUTD * 2);
    float*  Wt0   = (float*)alloc((size_t)HC * HC * 4);
    float*  Wt1   = (float*)alloc((size_t)HC * HC * 4);
    float*  Wct   = (float*)alloc((size_t)HC * OUTD * 4);
    float*  bc    = (float*)alloc((size_t)OUTD * 4);
    (void)ws_size; (void)in_sizes; (void)n_in; (void)out_size;

    const int LIN_NB = (N_NODES + 15) / 16;        // 3125
    const int EB_NB  = (N_EDGES + 8191) / 8192;    // 98
    const int PREP_N = HC * HC + HC * OUTD + OUTD;

    // weight prep (independent of everything else)
    k_prep<<<(PREP_N + 255) / 256, 256, 0, stream>>>(W0, W1, pW1, pb1, pW2, pb2,
                                                     Wt0, Wt1, Wct, bc);

    // bucketed CSR build
    hipMemsetAsync(bcnt, 0, (size_t)(NBKT + 1) * 4, stream);
    k_hist    <<<EB_NB, 1024, 0, stream>>>(dst, bcnt, N_EDGES);
    k_bscan   <<<1, 1024, 0, stream>>>(bcnt, bbase, bcur);
    k_bscatter<<<EB_NB, 1024, 0, stream>>>(src, dst, bcur, ebuf, N_EDGES);
    k_bfinal  <<<NBKT, 256, 0, stream>>>(ebuf, bbase, off, esrc, N_NODES);

    // GAT layer 0
    k_lin128<<<LIN_NB, 256, 0, stream>>>(emb, Wt0, b0, hbuf, N_NODES);
    k_gat_agg<<<(N_NODES + 3) / 4, 256, 0, stream>>>(hbuf, off, esrc, attl0, attr0,
                                                     xbuf, N_NODES, 0.01f);
    // GAT layer 1
    k_lin128<<<LIN_NB, 256, 0, stream>>>(xbuf, Wt1, b1, hbuf, N_NODES);
    k_gat_agg<<<(N_NODES + 3) / 4, 256, 0, stream>>>(hbuf, off, esrc, attl1, attr1,
                                                     xbuf, N_NODES, 0.01f);

    // post_mp (combined) + node output (fp32 + fp16 copy)
    k_lin64<<<LIN_NB, 256, 0, stream>>>(xbuf, Wct, bc, xo, yh, N_NODES);

    // edge scores
    k_edge_score<<<(N_EDGES * 8 + 255) / 256, 256, 0, stream>>>(yh, src, dst, out, N_EDGES);
}

// Round 11
// 193.389 us; speedup vs baseline: 1.8316x; 1.1964x over previous
//
#include <hip/hip_runtime.h>
#include <hip/hip_bf16.h>
#include <hip/hip_fp16.h>
#include <math.h>

#define N_NODES 50000
#define N_EDGES 800000
#define HC      128     // HEADS*HID
#define OUTD    64
#define NBKT    ((N_NODES + 63) / 64)   // 782 buckets of 64 nodes

// fast exp2: single v_exp_f32
#if defined(__has_builtin)
#if __has_builtin(__builtin_amdgcn_exp2f)
#define EXP2(x) __builtin_amdgcn_exp2f(x)
#endif
#endif
#ifndef EXP2
#define EXP2(x) __expf((x) * 0.69314718055994531f)
#endif

typedef _Float16 f16x8 __attribute__((ext_vector_type(8)));
typedef float f32x4 __attribute__((ext_vector_type(4)));

// ---------------- bucketed CSR build (round 8: WRITE_SIZE 51.6->~10MB) ------

__global__ __launch_bounds__(1024) void k_hist(const int* __restrict__ dst,
                                               int* __restrict__ bcnt, int e_cnt) {
    __shared__ int lh[NBKT];
    for (int i = threadIdx.x; i < NBKT; i += 1024) lh[i] = 0;
    __syncthreads();
    int base = blockIdx.x * 8192;
    for (int i = threadIdx.x; i < 8192; i += 1024) {
        int e = base + i;
        if (e < e_cnt) atomicAdd(&lh[dst[e] >> 6], 1);
    }
    __syncthreads();
    for (int i = threadIdx.x; i < NBKT; i += 1024) {
        int c = lh[i];
        if (c) atomicAdd(&bcnt[i], c);
    }
}

__global__ __launch_bounds__(1024) void k_bscan(const int* __restrict__ bcnt,
                                                int* __restrict__ bbase,
                                                int* __restrict__ bcur) {
    __shared__ int wsum[16];
    __shared__ int wexc[16];
    int t = threadIdx.x, lane = t & 63, wid = t >> 6;
    int v = (t < NBKT) ? bcnt[t] : 0;
    int incl = v;
    #pragma unroll
    for (int s = 1; s < 64; s <<= 1) {
        int u = __shfl_up(incl, s, 64);
        if (lane >= s) incl += u;
    }
    if (lane == 63) wsum[wid] = incl;
    __syncthreads();
    if (wid == 0 && lane < 16) {
        int w = wsum[lane];
        int wi = w;
        #pragma unroll
        for (int s = 1; s < 16; s <<= 1) {
            int u = __shfl_up(wi, s, 64);
            if (lane >= s) wi += u;
        }
        wexc[lane] = wi - w;
    }
    __syncthreads();
    int ex = wexc[wid] + incl - v;
    if (t < NBKT) { bbase[t] = ex; bcur[t] = ex; }
    if (t == NBKT - 1) bbase[NBKT] = ex + v;   // == e_cnt
}

__global__ __launch_bounds__(1024) void k_bscatter(const int* __restrict__ src,
                                                   const int* __restrict__ dst,
                                                   int* __restrict__ bcur,
                                                   uint2* __restrict__ ebuf, int e_cnt) {
    __shared__ int lcnt[NBKT];
    __shared__ int lbase[NBKT];
    for (int i = threadIdx.x; i < NBKT; i += 1024) lcnt[i] = 0;
    __syncthreads();
    int base = blockIdx.x * 8192;
    int myS[8], myD[8], myR[8];
    #pragma unroll
    for (int j = 0; j < 8; ++j) {
        int e = base + threadIdx.x + j * 1024;          // coalesced
        if (e < e_cnt) {
            myS[j] = src[e];
            myD[j] = dst[e];
            myR[j] = atomicAdd(&lcnt[myD[j] >> 6], 1);  // LDS rank (fast)
        } else myD[j] = -1;
    }
    __syncthreads();
    for (int i = threadIdx.x; i < NBKT; i += 1024) {
        int c = lcnt[i];
        lbase[i] = c ? atomicAdd(&bcur[i], c) : 0;      // reserve range once
    }
    __syncthreads();
    #pragma unroll
    for (int j = 0; j < 8; ++j) {
        if (myD[j] >= 0) {
            int bkt = myD[j] >> 6;
            ebuf[lbase[bkt] + myR[j]] =
                make_uint2((unsigned)myS[j], (unsigned)myD[j]);
        }
    }
}

__global__ __launch_bounds__(256) void k_bfinal(const uint2* __restrict__ ebuf,
                                                const int* __restrict__ bbase,
                                                int* __restrict__ off,
                                                int* __restrict__ esrc, int n) {
    __shared__ int ncnt[64];
    __shared__ int ncur[64];
    int b = blockIdx.x;
    int t = threadIdx.x;
    int ebeg = bbase[b], eend = bbase[b + 1];
    if (t < 64) ncnt[t] = 0;
    __syncthreads();
    for (int e = ebeg + t; e < eend; e += 256)
        atomicAdd(&ncnt[ebuf[e].y & 63], 1);
    __syncthreads();
    if (t < 64) {
        int v = ncnt[t];
        int incl = v;
        #pragma unroll
        for (int s = 1; s < 64; s <<= 1) {
            int u = __shfl_up(incl, s, 64);
            if (t >= s) incl += u;
        }
        int ex = incl - v;
        ncur[t] = ex;
        int node = b * 64 + t;
        if (node <= n) off[node] = ebeg + ex;   // covers off[n] via last bucket
    }
    __syncthreads();
    for (int e = ebeg + t; e < eend; e += 256) {
        uint2 ed = ebuf[e];
        int r = atomicAdd(&ncur[ed.y & 63], 1);
        esrc[ebeg + r] = (int)ed.x;             // contiguous 4KB region per block
    }
}

// ---------------- weight prep: fp16 copies of W0/W1 + post_mp combine --------
// W0/W1 are [out_ch][k] row-major -- exactly the B^T fragment layout the MFMA
// kernel wants; no transpose, just fp32->fp16 convert.

__global__ void k_prep(const float* __restrict__ W0, const float* __restrict__ W1,
                       const float* __restrict__ pW1, const float* __restrict__ pb1,
                       const float* __restrict__ pW2, const float* __restrict__ pb2,
                       __half* __restrict__ Wh0, __half* __restrict__ Wh1,
                       float* __restrict__ Wct, float* __restrict__ bc) {
    int i = blockIdx.x * blockDim.x + threadIdx.x;
    if (i < HC * HC) {
        Wh0[i] = __float2half(W0[i]);
        Wh1[i] = __float2half(W1[i]);
    } else if (i < HC * HC + HC * OUTD) {
        int j = i - HC * HC;
        int k = j >> 6, o2 = j & 63;
        float s = 0.f;
        for (int m = 0; m < 64; ++m) s += pW2[o2 * 64 + m] * pW1[m * 128 + k];
        Wct[k * 64 + o2] = s;
    } else if (i < HC * HC + HC * OUTD + OUTD) {
        int o2 = i - HC * HC - HC * OUTD;
        float s = pb2[o2];
        for (int m = 0; m < 64; ++m) s += pW2[o2 * 64 + m] * pb1[m];
        bc[o2] = s;
    }
}

// ---------------- linear via MFMA: h = x @ W^T + b, fp16 in, fp32 acc --------
// Round 11: rounds 9/10 showed the fp32 vector-FMA version pinned at ~45us by
// LDS-instruction throughput (6 ds_read_b128 per 32 FMA-instr). MFMA does
// 16384 FLOP per 2 operand reads. Block: 32 nodes x 128 ch, 4 waves, each
// wave one 16-node x 64-ch quadrant = 4 acc tiles, K=128 in 4 steps of 32.
// Fragment layout: A lane reads 8 contiguous k at row (l&15) of xsh;
// B same on Wh rows (gemm_bt pattern, m90/m92-verified); D: col=l&15,
// row=(l>>4)*4+reg (m89-verified, dtype-independent). LDS rows padded +8
// fp16 (stride 136) to break the 256B-stride bank conflict.

#define LSTR 136   // padded LDS row stride in fp16 elems

__global__ __launch_bounds__(256) void k_lin128(const float* __restrict__ x,
                                                const __half* __restrict__ Wh,
                                                const float* __restrict__ bias,
                                                __half* __restrict__ h, int n) {
    __shared__ _Float16 wsh[128 * LSTR];   // 34.0KB: W fp16, padded rows
    __shared__ _Float16 xsh[32 * LSTR];    // 8.5KB: x fp16 (reused for output)
    int t = threadIdx.x;
    int node0 = blockIdx.x * 32;
    // stage W: 128x128 fp16 in 16B chunks
    for (int i = t; i < 2048; i += 256) {
        int r = i >> 4, c16 = i & 15;
        *(uint4*)&wsh[r * LSTR + c16 * 8] = ((const uint4*)Wh)[i];
    }
    // stage x: 32 rows x 128 fp32 -> fp16
    for (int i = t; i < 1024; i += 256) {
        int r = i >> 5, c4 = i & 31;
        int gn = node0 + r;
        float4 v = (gn < n) ? ((const float4*)x)[(size_t)gn * 32 + c4]
                            : make_float4(0.f, 0.f, 0.f, 0.f);
        union { _Float16 hh[4]; uint2 u; } cv;
        cv.hh[0] = (_Float16)v.x; cv.hh[1] = (_Float16)v.y;
        cv.hh[2] = (_Float16)v.z; cv.hh[3] = (_Float16)v.w;
        *(uint2*)&xsh[r * LSTR + c4 * 4] = cv.u;
    }
    __syncthreads();
    int w = t >> 6, l = t & 63;
    int lr = l & 15, lg = l >> 4;          // row-in-tile, k-group
    int nrow0 = (w >> 1) * 16;             // node tile base (0 / 16)
    int ccol0 = (w & 1) * 64;              // ch tile base (0 / 64)
    f32x4 acc0 = {0.f, 0.f, 0.f, 0.f};
    f32x4 acc1 = acc0, acc2 = acc0, acc3 = acc0;
    #pragma unroll
    for (int kk = 0; kk < 4; ++kk) {
        int ko = kk * 32 + lg * 8;
        f16x8 a  = *(const f16x8*)&xsh[(nrow0 + lr) * LSTR + ko];
        f16x8 b0 = *(const f16x8*)&wsh[(ccol0 +  0 + lr) * LSTR + ko];
        f16x8 b1 = *(const f16x8*)&wsh[(ccol0 + 16 + lr) * LSTR + ko];
        f16x8 b2 = *(const f16x8*)&wsh[(ccol0 + 32 + lr) * LSTR + ko];
        f16x8 b3 = *(const f16x8*)&wsh[(ccol0 + 48 + lr) * LSTR + ko];
        acc0 = __builtin_amdgcn_mfma_f32_16x16x32_f16(a, b0, acc0, 0, 0, 0);
        acc1 = __builtin_amdgcn_mfma_f32_16x16x32_f16(a, b1, acc1, 0, 0, 0);
        acc2 = __builtin_amdgcn_mfma_f32_16x16x32_f16(a, b2, acc2, 0, 0, 0);
        acc3 = __builtin_amdgcn_mfma_f32_16x16x32_f16(a, b3, acc3, 0, 0, 0);
    }
    float b0v = bias[ccol0 +  0 + lr];
    float b1v = bias[ccol0 + 16 + lr];
    float b2v = bias[ccol0 + 32 + lr];
    float b3v = bias[ccol0 + 48 + lr];
    __syncthreads();                       // all xsh reads done before overwrite
    int orow = nrow0 + lg * 4;
    #pragma unroll
    for (int j = 0; j < 4; ++j) {
        xsh[(orow + j) * LSTR + ccol0 +  0 + lr] = (_Float16)(acc0[j] + b0v);
        xsh[(orow + j) * LSTR + ccol0 + 16 + lr] = (_Float16)(acc1[j] + b1v);
        xsh[(orow + j) * LSTR + ccol0 + 32 + lr] = (_Float16)(acc2[j] + b2v);
        xsh[(orow + j) * LSTR + ccol0 + 48 + lr] = (_Float16)(acc3[j] + b3v);
    }
    __syncthreads();
    // coalesced fp16 copy-out
    for (int i = t; i < 1024; i += 256) {
        int r = i >> 5, c4 = i & 31;
        int gn = node0 + r;
        if (gn < n)
            *(uint2*)&h[(size_t)gn * 128 + c4 * 4] = *(uint2*)&xsh[r * LSTR + c4 * 4];
    }
}

// ---------------- GAT aggregate (unchanged from round 9) ----------------

__global__ __launch_bounds__(256) void k_gat_agg(const __half* __restrict__ h,
                                                 const int* __restrict__ off,
                                                 const int* __restrict__ esrc,
                                                 const float* __restrict__ attl,
                                                 const float* __restrict__ attr,
                                                 float* __restrict__ xout, int n,
                                                 float neg_out) {
    const float L2E = 1.4426950408889634f;
    int wid  = threadIdx.x >> 6;
    int lane = threadIdx.x & 63;
    int node = blockIdx.x * 4 + wid;
    if (node >= n) return;
    int half = lane >> 5;               // edge parity this half-wave owns
    int cq   = lane & 31;               // channel quad index
    uint32_t cq8 = (uint32_t)cq << 3;   // byte offset of my 4 fp16 channels

    const char* hb = (const char*)h;    // uniform base (SGPR) -- saddr form

    float4 alv = ((const float4*)attl)[cq];
    float4 arv = ((const float4*)attr)[cq];
    uint2 hdr = *(const uint2*)(hb + ((((uint32_t)node << 8)) | cq8));
    float2 hd01 = __half22float2(((const __half2*)&hdr)[0]);
    float2 hd23 = __half22float2(((const __half2*)&hdr)[1]);
    float al0 = alv.x * L2E, al1 = alv.y * L2E;
    float al2 = alv.z * L2E, al3 = alv.w * L2E;
    float ar0 = arv.x * hd01.x * L2E, ar1 = arv.y * hd01.y * L2E;
    float ar2 = arv.z * hd23.x * L2E, ar3 = arv.w * hd23.y * L2E;

    float z0 = 0.f, z1 = 0.f, z2 = 0.f, z3 = 0.f;
    float a0 = 0.f, a1 = 0.f, a2 = 0.f, a3 = 0.f;

    int beg = off[node], end = off[node + 1];

#define STEP(sAv)                                                              \
    {   uint32_t voff = (((uint32_t)(sAv)) << 8) | cq8;                        \
        uint2 hv = *(const uint2*)(hb + voff);                                 \
        float2 f01 = __half22float2(((const __half2*)&hv)[0]);                 \
        float2 f23 = __half22float2(((const __half2*)&hv)[1]);                 \
        float t0 = fmaf(al0, f01.x, ar0), t1 = fmaf(al1, f01.y, ar1);          \
        float t2 = fmaf(al2, f23.x, ar2), t3 = fmaf(al3, f23.y, ar3);          \
        float e0 = EXP2(fmaxf(t0, 0.2f * t0)), e1 = EXP2(fmaxf(t1, 0.2f * t1));\
        float e2 = EXP2(fmaxf(t2, 0.2f * t2)), e3 = EXP2(fmaxf(t3, 0.2f * t3));\
        z0 += e0; z1 += e1; z2 += e2; z3 += e3;                                \
        a0 = fmaf(e0, f01.x, a0); a1 = fmaf(e1, f01.y, a1);                    \
        a2 = fmaf(e2, f23.x, a2); a3 = fmaf(e3, f23.y, a3);                    \
    }

    {
        int e = beg;
        #pragma unroll 4
        for (; e + 2 <= end; e += 2) {
            int sA = esrc[e + half];    // half-wave-uniform -> L1 broadcast
            STEP(sA);
        }
        if (e < end) {                  // one leftover edge (even parity)
            int sA = esrc[end - 1];
            if (half == 0) STEP(sA);
        }
    }
#undef STEP

    // validity: overflow -> z inf/NaN; total underflow -> z==0 with edges
    float zs = z0 + z1 + z2 + z3;
    bool bad = !(zs < 3.0e38f);
    if (beg < end)
        bad = bad || !((z0 > 0.f) && (z1 > 0.f) && (z2 > 0.f) && (z3 > 0.f));

    if (__any(bad)) {
        // slow safe path (~never): two-pass max-shifted softmax; every lane
        // walks ALL edges, so both halves hold identical full sums (no merge).
        float m0 = -1e30f, m1 = -1e30f, m2 = -1e30f, m3 = -1e30f;
        for (int e = beg; e < end; ++e) {
            int sA = esrc[e];
            uint2 hv = *(const uint2*)(hb + (((uint32_t)sA << 8) | cq8));
            float2 f01 = __half22float2(((const __half2*)&hv)[0]);
            float2 f23 = __half22float2(((const __half2*)&hv)[1]);
            float t0 = fmaf(al0, f01.x, ar0), t1 = fmaf(al1, f01.y, ar1);
            float t2 = fmaf(al2, f23.x, ar2), t3 = fmaf(al3, f23.y, ar3);
            m0 = fmaxf(m0, fmaxf(t0, 0.2f * t0));
            m1 = fmaxf(m1, fmaxf(t1, 0.2f * t1));
            m2 = fmaxf(m2, fmaxf(t2, 0.2f * t2));
            m3 = fmaxf(m3, fmaxf(t3, 0.2f * t3));
        }
        z0 = z1 = z2 = z3 = 0.f;
        a0 = a1 = a2 = a3 = 0.f;
        for (int e = beg; e < end; ++e) {
            int sA = esrc[e];
            uint2 hv = *(const uint2*)(hb + (((uint32_t)sA << 8) | cq8));
            float2 f01 = __half22float2(((const __half2*)&hv)[0]);
            float2 f23 = __half22float2(((const __half2*)&hv)[1]);
            float t0 = fmaf(al0, f01.x, ar0), t1 = fmaf(al1, f01.y, ar1);
            float t2 = fmaf(al2, f23.x, ar2), t3 = fmaf(al3, f23.y, ar3);
            float e0 = EXP2(fmaxf(t0, 0.2f * t0) - m0);
            float e1 = EXP2(fmaxf(t1, 0.2f * t1) - m1);
            float e2 = EXP2(fmaxf(t2, 0.2f * t2) - m2);
            float e3 = EXP2(fmaxf(t3, 0.2f * t3) - m3);
            z0 += e0; z1 += e1; z2 += e2; z3 += e3;
            a0 = fmaf(e0, f01.x, a0); a1 = fmaf(e1, f01.y, a1);
            a2 = fmaf(e2, f23.x, a2); a3 = fmaf(e3, f23.y, a3);
        }
    } else {
        // merge parity halves: plain adds (shared implicit reference)
        z0 += __shfl_xor(z0, 32, 64); z1 += __shfl_xor(z1, 32, 64);
        z2 += __shfl_xor(z2, 32, 64); z3 += __shfl_xor(z3, 32, 64);
        a0 += __shfl_xor(a0, 32, 64); a1 += __shfl_xor(a1, 32, 64);
        a2 += __shfl_xor(a2, 32, 64); a3 += __shfl_xor(a3, 32, 64);
    }

    if (half == 0) {
        float o0 = (z0 > 0.f) ? a0 / z0 : 0.f;
        float o1 = (z1 > 0.f) ? a1 / z1 : 0.f;
        float o2 = (z2 > 0.f) ? a2 / z2 : 0.f;
        float o3 = (z3 > 0.f) ? a3 / z3 : 0.f;
        o0 = fmaxf(o0, neg_out * o0);
        o1 = fmaxf(o1, neg_out * o1);
        o2 = fmaxf(o2, neg_out * o2);
        o3 = fmaxf(o3, neg_out * o3);
        *(float4*)&xout[(size_t)node * 128 + cq * 4] = make_float4(o0, o1, o2, o3);
    }
}

// ---------------- final linear K=128 -> 64: 24KB LDS (16 nodes, 2 chunks) ----

#define FMA4(acc, wv, sv)                                                      \
    acc.x = fmaf(wv.x, sv, acc.x); acc.y = fmaf(wv.y, sv, acc.y);              \
    acc.z = fmaf(wv.z, sv, acc.z); acc.w = fmaf(wv.w, sv, acc.w);

__global__ __launch_bounds__(256) void k_lin64(const float* __restrict__ x,
                                               const float* __restrict__ Wct,
                                               const float* __restrict__ bc,
                                               float* __restrict__ y,
                                               __half* __restrict__ yh, int n) {
    __shared__ float ws[64 * 64];       // 16KB: one K-chunk of Wct (64 k-rows)
    __shared__ float xs[16 * 128];      // 8KB
    int t = threadIdx.x;
    int node0 = blockIdx.x * 16;
    for (int i = t; i < 512; i += 256) {
        int row = i >> 5, c = i & 31;
        int gn = node0 + row;
        ((float4*)xs)[i] = (gn < n) ? ((const float4*)x)[(size_t)gn * 32 + c]
                                    : make_float4(0.f, 0.f, 0.f, 0.f);
    }
    int l = t & 15;                     // output float4 index [0,16)
    int g = t >> 4;                     // my node [0,16)
    float4 acc = ((const float4*)bc)[l];
    const float4* xr = (const float4*)&xs[g * 128];

    for (int chunk = 0; chunk < 2; ++chunk) {
        __syncthreads();
        const float4* wsrc = (const float4*)&Wct[chunk * 64 * 64];
        for (int i = t; i < 1024; i += 256)
            ((float4*)ws)[i] = wsrc[i];
        __syncthreads();
        int kb = chunk * 16;
        #pragma unroll 4
        for (int k4 = 0; k4 < 16; ++k4) {
            float4 xv = xr[kb + k4];
            const float* wr = &ws[k4 * 256];
            float4 w0 = ((const float4*)&wr[0])[l];
            float4 w1 = ((const float4*)&wr[64])[l];
            float4 w2 = ((const float4*)&wr[128])[l];
            float4 w3 = ((const float4*)&wr[192])[l];
            FMA4(acc, w0, xv.x); FMA4(acc, w1, xv.y);
            FMA4(acc, w2, xv.z); FMA4(acc, w3, xv.w);
        }
    }

    int gn = node0 + g;
    if (gn < n) {
        ((float4*)&y[(size_t)gn * 64])[l] = acc;
        union { __half2 h2[2]; uint2 u; } p;
        p.h2[0] = __floats2half2_rn(acc.x, acc.y);
        p.h2[1] = __floats2half2_rn(acc.z, acc.w);
        *(uint2*)&yh[(size_t)gn * 64 + l * 4] = p.u;
    }
}

// ---------------- edge scores: sigmoid(dot(x[src], x[dst])), fp16 gather, 8 lanes/edge ----------------

__global__ __launch_bounds__(256) void k_edge_score(const __half* __restrict__ xh,
                                                    const int* __restrict__ src,
                                                    const int* __restrict__ dst,
                                                    float* __restrict__ out, int e_cnt) {
    int t = blockIdx.x * 256 + threadIdx.x;
    int e = t >> 3;
    int l = t & 7;
    if (e >= e_cnt) return;
    int u = src[e], v = dst[e];
    uint4 ua = ((const uint4*)&xh[(size_t)u * 64])[l];
    uint4 vb = ((const uint4*)&xh[(size_t)v * 64])[l];
    const __half2* pa = (const __half2*)&ua;
    const __half2* pb = (const __half2*)&vb;
    float d = 0.f;
    #pragma unroll
    for (int j = 0; j < 4; ++j) {
        float2 fa = __half22float2(pa[j]);
        float2 fb = __half22float2(pb[j]);
        d = fmaf(fa.x, fb.x, d);
        d = fmaf(fa.y, fb.y, d);
    }
    d += __shfl_xor(d, 1);
    d += __shfl_xor(d, 2);
    d += __shfl_xor(d, 4);
    if (l == 0) out[e] = 1.f / (1.f + __expf(-d));
}

// ---------------- launch ----------------

extern "C" void kernel_launch(void* const* d_in, const int* in_sizes, int n_in,
                              void* d_out, int out_size, void* d_ws, size_t ws_size,
                              hipStream_t stream) {
    const float* emb   = (const float*)d_in[0];
    const int*   ei    = (const int*)d_in[1];
    const float* W0    = (const float*)d_in[2];
    const float* b0    = (const float*)d_in[3];
    const float* attl0 = (const float*)d_in[4];
    const float* attr0 = (const float*)d_in[5];
    const float* W1    = (const float*)d_in[6];
    const float* b1    = (const float*)d_in[7];
    const float* attl1 = (const float*)d_in[8];
    const float* attr1 = (const float*)d_in[9];
    const float* pW1   = (const float*)d_in[10];
    const float* pb1   = (const float*)d_in[11];
    const float* pW2   = (const float*)d_in[12];
    const float* pb2   = (const float*)d_in[13];

    const int* src = ei;
    const int* dst = ei + N_EDGES;

    float* out = (float*)d_out;          // [E]
    float* xo  = out + N_EDGES;          // [N,64] fp32 node output

    char* ws = (char*)d_ws;
    size_t o = 0;
    auto alloc = [&](size_t bytes) {
        char* p = ws + o;
        o = (o + bytes + 255) & ~(size_t)255;
        return p;
    };
    int*    off   = (int*)alloc((size_t)(N_NODES + 1) * 4);
    int*    esrc  = (int*)alloc((size_t)N_EDGES * 4);
    int*    bcnt  = (int*)alloc((size_t)(NBKT + 1) * 4);
    int*    bbase = (int*)alloc((size_t)(NBKT + 1) * 4);
    int*    bcur  = (int*)alloc((size_t)(NBKT + 1) * 4);
    uint2*  ebuf  = (uint2*)alloc((size_t)N_EDGES * 8);
    __half* hbuf  = (__half*)alloc((size_t)N_NODES * HC * 2);
    float*  xbuf  = (float*)alloc((size_t)N_NODES * HC * 4);
    __half* yh    = (__half*)alloc((size_t)N_NODES * OUTD * 2);
    __half* Wh0   = (__half*)alloc((size_t)HC * HC * 2);
    __half* Wh1   = (__half*)alloc((size_t)HC * HC * 2);
    float*  Wct   = (float*)alloc((size_t)HC * OUTD * 4);
    float*  bc    = (float*)alloc((size_t)OUTD * 4);
    (void)ws_size; (void)in_sizes; (void)n_in; (void)out_size;

    const int L128_NB = (N_NODES + 31) / 32;       // 1563
    const int L64_NB  = (N_NODES + 15) / 16;       // 3125
    const int EB_NB   = (N_EDGES + 8191) / 8192;   // 98
    const int PREP_N  = HC * HC + HC * OUTD + OUTD;

    // weight prep (independent of everything else)
    k_prep<<<(PREP_N + 255) / 256, 256, 0, stream>>>(W0, W1, pW1, pb1, pW2, pb2,
                                                     Wh0, Wh1, Wct, bc);

    // bucketed CSR build
    hipMemsetAsync(bcnt, 0, (size_t)(NBKT + 1) * 4, stream);
    k_hist    <<<EB_NB, 1024, 0, stream>>>(dst, bcnt, N_EDGES);
    k_bscan   <<<1, 1024, 0, stream>>>(bcnt, bbase, bcur);
    k_bscatter<<<EB_NB, 1024, 0, stream>>>(src, dst, bcur, ebuf, N_EDGES);
    k_bfinal  <<<NBKT, 256, 0, stream>>>(ebuf, bbase, off, esrc, N_NODES);

    // GAT layer 0
    k_lin128<<<L128_NB, 256, 0, stream>>>(emb, Wh0, b0, hbuf, N_NODES);
    k_gat_agg<<<(N_NODES + 3) / 4, 256, 0, stream>>>(hbuf, off, esrc, attl0, attr0,
                                                     xbuf, N_NODES, 0.01f);
    // GAT layer 1
    k_lin128<<<L128_NB, 256, 0, stream>>>(xbuf, Wh1, b1, hbuf, N_NODES);
    k_gat_agg<<<(N_NODES + 3) / 4, 256, 0, stream>>>(hbuf, off, esrc, attl1, attr1,
                                                     xbuf, N_NODES, 0.01f);

    // post_mp (combined) + node output (fp32 + fp16 copy)
    k_lin64<<<L64_NB, 256, 0, stream>>>(xbuf, Wct, bc, xo, yh, N_NODES);

    // edge scores
    k_edge_score<<<(N_EDGES * 8 + 255) / 256, 256, 0, stream>>>(yh, src, dst, out, N_EDGES);
}